// Round 1
// baseline (1127.377 us; speedup 1.0000x reference)
//
#include <hip/hip_runtime.h>
#include <math.h>

// GCN 3-layer: out[d] = dinv[d]*(sum_{s->d} g[s] + g[d]) + b,  g = (x@W)*dinv[row]
// CSR built once per launch (deg identical across layers).

#define IN_DIM 128
#define HID 64
#define OUT_DIM 112

__global__ __launch_bounds__(256) void count_kernel(const int* __restrict__ dst,
                                                    int* __restrict__ cnt, int E) {
  int i = blockIdx.x * 256 + threadIdx.x;
  if (i < E) atomicAdd(&cnt[dst[i]], 1);
}

__global__ __launch_bounds__(256) void dinv_kernel(const int* __restrict__ cnt,
                                                   float* __restrict__ dinv, int n) {
  int i = blockIdx.x * 256 + threadIdx.x;
  if (i < n) dinv[i] = 1.0f / sqrtf((float)(cnt[i] + 1));  // +1 = self loop
}

// Single-block chunked exclusive scan: row_start[i] = sum(cnt[0..i)), also copies
// into cursor (fill_kernel's atomic cursors). cnt and cursor may alias.
__global__ __launch_bounds__(1024) void scan_kernel(const int* __restrict__ cnt,
                                                    int* __restrict__ row_start,
                                                    int* __restrict__ cursor, int n) {
  const int T = 1024;
  int t = threadIdx.x;
  int ipt = (n + T - 1) / T;
  int lo = t * ipt;
  int hi = min(n, lo + ipt);
  int sum = 0;
  for (int i = lo; i < hi; ++i) sum += cnt[i];
  __shared__ int sh[T];
  sh[t] = sum;
  __syncthreads();
  for (int off = 1; off < T; off <<= 1) {
    int v = (t >= off) ? sh[t - off] : 0;
    __syncthreads();
    sh[t] += v;
    __syncthreads();
  }
  int run = sh[t] - sum;  // exclusive prefix of this thread's chunk
  for (int i = lo; i < hi; ++i) {
    int cv = cnt[i];          // read BEFORE writing cursor (may alias)
    row_start[i] = run;
    cursor[i] = run;
    run += cv;
  }
  if (t == 0) row_start[n] = sh[T - 1];
}

__global__ __launch_bounds__(256) void fill_kernel(const int* __restrict__ src,
                                                   const int* __restrict__ dst,
                                                   int* __restrict__ cursor,
                                                   int* __restrict__ ssrc, int E) {
  int i = blockIdx.x * 256 + threadIdx.x;
  if (i < E) {
    int p = atomicAdd(&cursor[dst[i]], 1);
    ssrc[p] = src[i];
  }
}

// G[r][c] = (X[r][:] . W[:][c]) * dinv[r].  Wave = 16 rows x up-to-64 cols.
// x addresses are wave-uniform (readfirstlane'd wave id) -> scalar loads.
template <int K, int C>
__global__ __launch_bounds__(256) void gemm_scale_kernel(const float* __restrict__ X,
                                                         const float* __restrict__ W,
                                                         const float* __restrict__ dinv,
                                                         float* __restrict__ G, int n) {
  constexpr int CG = (C + 63) / 64;        // col groups (1 for C=64, 2 for C=112)
  constexpr int RPB = (4 / CG) * 16;       // rows per block (64 or 32)
  __shared__ float Ws[K * C];
  for (int i = threadIdx.x; i < K * C; i += 256) Ws[i] = W[i];
  __syncthreads();

  int wave = __builtin_amdgcn_readfirstlane((int)(threadIdx.x >> 6));
  int lane = threadIdx.x & 63;
  int rg = wave / CG, cg = wave % CG;
  int c = cg * 64 + lane;
  int cl = (c < C) ? c : (C - 1);          // clamped for LDS reads; store guarded
  int rbase = blockIdx.x * RPB + rg * 16;

  float acc[16];
#pragma unroll
  for (int r = 0; r < 16; ++r) acc[r] = 0.f;

  for (int k = 0; k < K; k += 4) {
    float w0 = Ws[(k + 0) * C + cl];
    float w1 = Ws[(k + 1) * C + cl];
    float w2 = Ws[(k + 2) * C + cl];
    float w3 = Ws[(k + 3) * C + cl];
#pragma unroll
    for (int r = 0; r < 16; ++r) {
      int row = rbase + r;
      if (row >= n) row = n - 1;           // clamp tail loads (store guarded)
      const float4 xv = *reinterpret_cast<const float4*>(&X[(size_t)row * K + k]);
      acc[r] = fmaf(xv.w, w3, fmaf(xv.z, w2, fmaf(xv.y, w1, fmaf(xv.x, w0, acc[r]))));
    }
  }
#pragma unroll
  for (int r = 0; r < 16; ++r) {
    int row = rbase + r;
    if (row < n && c < C) G[(size_t)row * C + c] = acc[r] * dinv[row];
  }
}

// out[d][c] = [relu]( dinv[d]*(g[d][c] + sum_{e in row d} g[ssrc[e]][c]) + bias[c] )
template <int C, bool RELU>
__global__ __launch_bounds__(256) void agg_kernel(const float* __restrict__ g,
                                                  const int* __restrict__ row_start,
                                                  const int* __restrict__ ssrc,
                                                  const float* __restrict__ dinv,
                                                  const float* __restrict__ bias,
                                                  float* __restrict__ out, int n) {
  constexpr int TPN = (C <= 64) ? 64 : 128;  // threads per node
  constexpr int NPB = 256 / TPN;             // nodes per block
  int local = threadIdx.x / TPN;
  int c = threadIdx.x % TPN;
  int node = blockIdx.x * NPB + local;
  if (node >= n || c >= C) return;
  int e0 = row_start[node];
  int e1 = row_start[node + 1];
  float acc = g[(size_t)node * C + c];       // self-loop term
  int e = e0;
  for (; e + 3 < e1; e += 4) {
    int s0 = ssrc[e + 0], s1 = ssrc[e + 1], s2 = ssrc[e + 2], s3 = ssrc[e + 3];
    float v0 = g[(size_t)s0 * C + c];
    float v1 = g[(size_t)s1 * C + c];
    float v2 = g[(size_t)s2 * C + c];
    float v3 = g[(size_t)s3 * C + c];
    acc += v0; acc += v1; acc += v2; acc += v3;
  }
  for (; e < e1; ++e) acc += g[(size_t)ssrc[e] * C + c];
  float r = acc * dinv[node] + bias[c];
  if (RELU) r = fmaxf(r, 0.f);
  out[(size_t)node * C + c] = r;
}

extern "C" void kernel_launch(void* const* d_in, const int* in_sizes, int n_in,
                              void* d_out, int out_size, void* d_ws, size_t ws_size,
                              hipStream_t stream) {
  const float* x = (const float*)d_in[0];
  const int* ei = (const int*)d_in[1];
  const float* W1 = (const float*)d_in[2];
  const float* b1 = (const float*)d_in[3];
  const float* W2 = (const float*)d_in[4];
  const float* b2 = (const float*)d_in[5];
  const float* W3 = (const float*)d_in[6];
  const float* b3 = (const float*)d_in[7];
  float* out = (float*)d_out;

  const int n = in_sizes[0] / IN_DIM;  // 100000
  const int E = in_sizes[1] / 2;       // 1600000
  const int* src = ei;
  const int* dst = ei + E;

  char* p = (char*)d_ws;
  auto alloc = [&](size_t bytes) {
    char* q = p;
    p += (bytes + 255) & ~(size_t)255;
    return q;
  };
  float* dinv = (float*)alloc((size_t)n * 4);
  int* row_start = (int*)alloc((size_t)(n + 1) * 4);
  int* cursor = (int*)alloc((size_t)n * 4);
  int* ssrc = (int*)alloc((size_t)E * 4);
  float* bufG = (float*)alloc((size_t)n * OUT_DIM * 4);  // max cols = 112
  float* bufH = (float*)alloc((size_t)n * HID * 4);

  // ---- CSR build (once; shared by all 3 layers) ----
  hipMemsetAsync(cursor, 0, (size_t)n * 4, stream);
  count_kernel<<<(E + 255) / 256, 256, 0, stream>>>(dst, cursor, E);
  dinv_kernel<<<(n + 255) / 256, 256, 0, stream>>>(cursor, dinv, n);
  scan_kernel<<<1, 1024, 0, stream>>>(cursor, row_start, cursor, n);
  fill_kernel<<<(E + 255) / 256, 256, 0, stream>>>(src, dst, cursor, ssrc, E);

  // ---- layer 1: 128 -> 64, relu ----
  gemm_scale_kernel<IN_DIM, HID><<<(n + 63) / 64, 256, 0, stream>>>(x, W1, dinv, bufG, n);
  agg_kernel<HID, true><<<(n + 3) / 4, 256, 0, stream>>>(bufG, row_start, ssrc, dinv, b1, bufH, n);

  // ---- layer 2: 64 -> 64, relu ----
  gemm_scale_kernel<HID, HID><<<(n + 63) / 64, 256, 0, stream>>>(bufH, W2, dinv, bufG, n);
  agg_kernel<HID, true><<<(n + 3) / 4, 256, 0, stream>>>(bufG, row_start, ssrc, dinv, b2, bufH, n);

  // ---- layer 3: 64 -> 112, no relu ----
  gemm_scale_kernel<HID, OUT_DIM><<<(n + 31) / 32, 256, 0, stream>>>(bufH, W3, dinv, bufG, n);
  agg_kernel<OUT_DIM, false><<<(n + 1) / 2, 256, 0, stream>>>(bufG, row_start, ssrc, dinv, b3, out, n);
}

// Round 2
// 884.466 us; speedup vs baseline: 1.2746x; 1.2746x over previous
//
#include <hip/hip_runtime.h>
#include <math.h>

// GCN 3-layer: out[d] = dinv[d]*(sum_{s->d} g[s] + g[d]) + b,  g = (x@W)*dinv[row]
// CSR built once per launch (deg identical across layers).

#define IN_DIM 128
#define HID 64
#define OUT_DIM 112
#define SCAN_TILE 1024  // elems per scan block: 256 threads x 4

__global__ __launch_bounds__(256) void count_kernel(const int* __restrict__ dst,
                                                    int* __restrict__ cnt, int E) {
  int i = blockIdx.x * 256 + threadIdx.x;
  if (i < E) atomicAdd(&cnt[dst[i]], 1);
}

__global__ __launch_bounds__(256) void dinv_kernel(const int* __restrict__ cnt,
                                                   float* __restrict__ dinv, int n) {
  int i = blockIdx.x * 256 + threadIdx.x;
  if (i < n) dinv[i] = 1.0f / sqrtf((float)(cnt[i] + 1));  // +1 = self loop
}

// ---- hierarchical exclusive scan (replaces 233us single-block scan) ----

__global__ __launch_bounds__(256) void scan_partial_kernel(const int* __restrict__ cnt,
                                                           int* __restrict__ blocksum,
                                                           int n) {
  int t = threadIdx.x;
  int base = blockIdx.x * SCAN_TILE + t * 4;
  int s = 0;
  if (base + 4 <= n) {
    int4 v = *reinterpret_cast<const int4*>(&cnt[base]);
    s = v.x + v.y + v.z + v.w;
  } else {
    for (int i = 0; i < 4; ++i)
      if (base + i < n) s += cnt[base + i];
  }
#pragma unroll
  for (int off = 1; off < 64; off <<= 1) s += __shfl_xor(s, off);
  __shared__ int wsum[4];
  int lane = t & 63, wv = t >> 6;
  if (lane == 0) wsum[wv] = s;
  __syncthreads();
  if (t == 0) blocksum[blockIdx.x] = wsum[0] + wsum[1] + wsum[2] + wsum[3];
}

// single small block: exclusive scan of blocksum[0..nb) in place; total -> *total_out
__global__ __launch_bounds__(1024) void scan_blocksums_kernel(int* __restrict__ blocksum,
                                                              int* __restrict__ total_out,
                                                              int nb) {
  __shared__ int sh[1024];
  int t = threadIdx.x;
  int v = (t < nb) ? blocksum[t] : 0;
  sh[t] = v;
  __syncthreads();
  for (int off = 1; off < 1024; off <<= 1) {
    int u = (t >= off) ? sh[t - off] : 0;
    __syncthreads();
    sh[t] += u;
    __syncthreads();
  }
  if (t < nb) blocksum[t] = sh[t] - v;  // exclusive
  if (t == 1023) *total_out = sh[1023]; // grand total
}

// re-read tile, block-level exclusive scan + tile offset, write row_start & cursor.
// cnt may alias cursor: each thread reads its 4 elems before writing them.
__global__ __launch_bounds__(256) void scan_final_kernel(const int* __restrict__ cnt,
                                                         const int* __restrict__ blocksum,
                                                         int* __restrict__ row_start,
                                                         int* __restrict__ cursor, int n) {
  int t = threadIdx.x;
  int base = blockIdx.x * SCAN_TILE + t * 4;
  int v0 = 0, v1 = 0, v2 = 0, v3 = 0;
  if (base + 4 <= n) {
    int4 v = *reinterpret_cast<const int4*>(&cnt[base]);
    v0 = v.x; v1 = v.y; v2 = v.z; v3 = v.w;
  } else {
    if (base + 0 < n) v0 = cnt[base + 0];
    if (base + 1 < n) v1 = cnt[base + 1];
    if (base + 2 < n) v2 = cnt[base + 2];
    if (base + 3 < n) v3 = cnt[base + 3];
  }
  int s = v0 + v1 + v2 + v3;
  __shared__ int sh[256];
  sh[t] = s;
  __syncthreads();
  for (int off = 1; off < 256; off <<= 1) {
    int u = (t >= off) ? sh[t - off] : 0;
    __syncthreads();
    sh[t] += u;
    __syncthreads();
  }
  int run = blocksum[blockIdx.x] + sh[t] - s;  // exclusive prefix for this thread
  int p0 = run, p1 = run + v0, p2 = p1 + v1, p3 = p2 + v2;
  if (base + 4 <= n) {
    *reinterpret_cast<int4*>(&row_start[base]) = make_int4(p0, p1, p2, p3);
    *reinterpret_cast<int4*>(&cursor[base]) = make_int4(p0, p1, p2, p3);
  } else {
    if (base + 0 < n) { row_start[base + 0] = p0; cursor[base + 0] = p0; }
    if (base + 1 < n) { row_start[base + 1] = p1; cursor[base + 1] = p1; }
    if (base + 2 < n) { row_start[base + 2] = p2; cursor[base + 2] = p2; }
    if (base + 3 < n) { row_start[base + 3] = p3; cursor[base + 3] = p3; }
  }
}

__global__ __launch_bounds__(256) void fill_kernel(const int* __restrict__ src,
                                                   const int* __restrict__ dst,
                                                   int* __restrict__ cursor,
                                                   int* __restrict__ ssrc, int E) {
  int i = blockIdx.x * 256 + threadIdx.x;
  if (i < E) {
    int p = atomicAdd(&cursor[dst[i]], 1);
    ssrc[p] = src[i];
  }
}

// G[r][c] = (X[r][:] . W[:][c]) * dinv[r].  Wave = 16 rows x up-to-64 cols.
template <int K, int C>
__global__ __launch_bounds__(256) void gemm_scale_kernel(const float* __restrict__ X,
                                                         const float* __restrict__ W,
                                                         const float* __restrict__ dinv,
                                                         float* __restrict__ G, int n) {
  constexpr int CG = (C + 63) / 64;        // col groups (1 for C=64, 2 for C=112)
  constexpr int RPB = (4 / CG) * 16;       // rows per block (64 or 32)
  __shared__ float Ws[K * C];
  for (int i = threadIdx.x; i < K * C; i += 256) Ws[i] = W[i];
  __syncthreads();

  int wave = __builtin_amdgcn_readfirstlane((int)(threadIdx.x >> 6));
  int lane = threadIdx.x & 63;
  int rg = wave / CG, cg = wave % CG;
  int c = cg * 64 + lane;
  int cl = (c < C) ? c : (C - 1);          // clamped for LDS reads; store guarded
  int rbase = blockIdx.x * RPB + rg * 16;

  float acc[16];
#pragma unroll
  for (int r = 0; r < 16; ++r) acc[r] = 0.f;

  for (int k = 0; k < K; k += 4) {
    float w0 = Ws[(k + 0) * C + cl];
    float w1 = Ws[(k + 1) * C + cl];
    float w2 = Ws[(k + 2) * C + cl];
    float w3 = Ws[(k + 3) * C + cl];
#pragma unroll
    for (int r = 0; r < 16; ++r) {
      int row = rbase + r;
      if (row >= n) row = n - 1;           // clamp tail loads (store guarded)
      const float4 xv = *reinterpret_cast<const float4*>(&X[(size_t)row * K + k]);
      acc[r] = fmaf(xv.w, w3, fmaf(xv.z, w2, fmaf(xv.y, w1, fmaf(xv.x, w0, acc[r]))));
    }
  }
#pragma unroll
  for (int r = 0; r < 16; ++r) {
    int row = rbase + r;
    if (row < n && c < C) G[(size_t)row * C + c] = acc[r] * dinv[row];
  }
}

// out[d][c] = [relu]( dinv[d]*(g[d][c] + sum_{e in row d} g[ssrc[e]][c]) + bias[c] )
template <int C, bool RELU>
__global__ __launch_bounds__(256) void agg_kernel(const float* __restrict__ g,
                                                  const int* __restrict__ row_start,
                                                  const int* __restrict__ ssrc,
                                                  const float* __restrict__ dinv,
                                                  const float* __restrict__ bias,
                                                  float* __restrict__ out, int n) {
  constexpr int TPN = (C <= 64) ? 64 : 128;  // threads per node
  constexpr int NPB = 256 / TPN;             // nodes per block
  int local = threadIdx.x / TPN;
  int c = threadIdx.x % TPN;
  int node = blockIdx.x * NPB + local;
  if (node >= n || c >= C) return;
  int e0 = row_start[node];
  int e1 = row_start[node + 1];
  float acc = g[(size_t)node * C + c];       // self-loop term
  int e = e0;
  for (; e + 3 < e1; e += 4) {
    int s0 = ssrc[e + 0], s1 = ssrc[e + 1], s2 = ssrc[e + 2], s3 = ssrc[e + 3];
    float v0 = g[(size_t)s0 * C + c];
    float v1 = g[(size_t)s1 * C + c];
    float v2 = g[(size_t)s2 * C + c];
    float v3 = g[(size_t)s3 * C + c];
    acc += v0; acc += v1; acc += v2; acc += v3;
  }
  for (; e < e1; ++e) acc += g[(size_t)ssrc[e] * C + c];
  float r = acc * dinv[node] + bias[c];
  if (RELU) r = fmaxf(r, 0.f);
  out[(size_t)node * C + c] = r;
}

extern "C" void kernel_launch(void* const* d_in, const int* in_sizes, int n_in,
                              void* d_out, int out_size, void* d_ws, size_t ws_size,
                              hipStream_t stream) {
  const float* x = (const float*)d_in[0];
  const int* ei = (const int*)d_in[1];
  const float* W1 = (const float*)d_in[2];
  const float* b1 = (const float*)d_in[3];
  const float* W2 = (const float*)d_in[4];
  const float* b2 = (const float*)d_in[5];
  const float* W3 = (const float*)d_in[6];
  const float* b3 = (const float*)d_in[7];
  float* out = (float*)d_out;

  const int n = in_sizes[0] / IN_DIM;  // 100000
  const int E = in_sizes[1] / 2;       // 1600000
  const int* src = ei;
  const int* dst = ei + E;

  char* p = (char*)d_ws;
  auto alloc = [&](size_t bytes) {
    char* q = p;
    p += (bytes + 255) & ~(size_t)255;
    return q;
  };
  float* dinv = (float*)alloc((size_t)n * 4);
  int* row_start = (int*)alloc((size_t)(n + 1) * 4);
  int* cursor = (int*)alloc((size_t)n * 4);      // doubles as cnt
  int* blocksum = (int*)alloc((size_t)1024 * 4);
  int* ssrc = (int*)alloc((size_t)E * 4);
  float* bufG = (float*)alloc((size_t)n * OUT_DIM * 4);  // max cols = 112
  float* bufH = (float*)alloc((size_t)n * HID * 4);

  const int NB = (n + SCAN_TILE - 1) / SCAN_TILE;  // 98 for n=100000

  // ---- CSR build (once; shared by all 3 layers) ----
  hipMemsetAsync(cursor, 0, (size_t)n * 4, stream);
  count_kernel<<<(E + 255) / 256, 256, 0, stream>>>(dst, cursor, E);
  dinv_kernel<<<(n + 255) / 256, 256, 0, stream>>>(cursor, dinv, n);
  scan_partial_kernel<<<NB, 256, 0, stream>>>(cursor, blocksum, n);
  scan_blocksums_kernel<<<1, 1024, 0, stream>>>(blocksum, &row_start[n], NB);
  scan_final_kernel<<<NB, 256, 0, stream>>>(cursor, blocksum, row_start, cursor, n);
  fill_kernel<<<(E + 255) / 256, 256, 0, stream>>>(src, dst, cursor, ssrc, E);

  // ---- layer 1: 128 -> 64, relu ----
  gemm_scale_kernel<IN_DIM, HID><<<(n + 63) / 64, 256, 0, stream>>>(x, W1, dinv, bufG, n);
  agg_kernel<HID, true><<<(n + 3) / 4, 256, 0, stream>>>(bufG, row_start, ssrc, dinv, b1, bufH, n);

  // ---- layer 2: 64 -> 64, relu ----
  gemm_scale_kernel<HID, HID><<<(n + 63) / 64, 256, 0, stream>>>(bufH, W2, dinv, bufG, n);
  agg_kernel<HID, true><<<(n + 3) / 4, 256, 0, stream>>>(bufG, row_start, ssrc, dinv, b2, bufH, n);

  // ---- layer 3: 64 -> 112, no relu ----
  gemm_scale_kernel<HID, OUT_DIM><<<(n + 31) / 32, 256, 0, stream>>>(bufH, W3, dinv, bufG, n);
  agg_kernel<OUT_DIM, false><<<(n + 1) / 2, 256, 0, stream>>>(bufG, row_start, ssrc, dinv, b3, out, n);
}

// Round 3
// 722.076 us; speedup vs baseline: 1.5613x; 1.2249x over previous
//
#include <hip/hip_runtime.h>
#include <math.h>

// GCN 3-layer: out[d] = dinv[d]*(sum_{s->d} g[s] + g[d]) + b,  g = (x@W)*dinv[row]
// CSR built once per launch (deg identical across layers).

#define IN_DIM 128
#define HID 64
#define OUT_DIM 112
#define SCAN_TILE 1024  // elems per scan block: 256 threads x 4

__global__ __launch_bounds__(256) void count_kernel(const int* __restrict__ dst,
                                                    int* __restrict__ cnt, int E) {
  int i = blockIdx.x * 256 + threadIdx.x;
  if (i < E) atomicAdd(&cnt[dst[i]], 1);
}

__global__ __launch_bounds__(256) void dinv_kernel(const int* __restrict__ cnt,
                                                   float* __restrict__ dinv, int n) {
  int i = blockIdx.x * 256 + threadIdx.x;
  if (i < n) dinv[i] = 1.0f / sqrtf((float)(cnt[i] + 1));  // +1 = self loop
}

// ---- hierarchical exclusive scan ----

__global__ __launch_bounds__(256) void scan_partial_kernel(const int* __restrict__ cnt,
                                                           int* __restrict__ blocksum,
                                                           int n) {
  int t = threadIdx.x;
  int base = blockIdx.x * SCAN_TILE + t * 4;
  int s = 0;
  if (base + 4 <= n) {
    int4 v = *reinterpret_cast<const int4*>(&cnt[base]);
    s = v.x + v.y + v.z + v.w;
  } else {
    for (int i = 0; i < 4; ++i)
      if (base + i < n) s += cnt[base + i];
  }
#pragma unroll
  for (int off = 1; off < 64; off <<= 1) s += __shfl_xor(s, off);
  __shared__ int wsum[4];
  int lane = t & 63, wv = t >> 6;
  if (lane == 0) wsum[wv] = s;
  __syncthreads();
  if (t == 0) blocksum[blockIdx.x] = wsum[0] + wsum[1] + wsum[2] + wsum[3];
}

__global__ __launch_bounds__(1024) void scan_blocksums_kernel(int* __restrict__ blocksum,
                                                              int* __restrict__ total_out,
                                                              int nb) {
  __shared__ int sh[1024];
  int t = threadIdx.x;
  int v = (t < nb) ? blocksum[t] : 0;
  sh[t] = v;
  __syncthreads();
  for (int off = 1; off < 1024; off <<= 1) {
    int u = (t >= off) ? sh[t - off] : 0;
    __syncthreads();
    sh[t] += u;
    __syncthreads();
  }
  if (t < nb) blocksum[t] = sh[t] - v;  // exclusive
  if (t == 1023) *total_out = sh[1023]; // grand total
}

__global__ __launch_bounds__(256) void scan_final_kernel(const int* __restrict__ cnt,
                                                         const int* __restrict__ blocksum,
                                                         int* __restrict__ row_start,
                                                         int* __restrict__ cursor, int n) {
  int t = threadIdx.x;
  int base = blockIdx.x * SCAN_TILE + t * 4;
  int v0 = 0, v1 = 0, v2 = 0, v3 = 0;
  if (base + 4 <= n) {
    int4 v = *reinterpret_cast<const int4*>(&cnt[base]);
    v0 = v.x; v1 = v.y; v2 = v.z; v3 = v.w;
  } else {
    if (base + 0 < n) v0 = cnt[base + 0];
    if (base + 1 < n) v1 = cnt[base + 1];
    if (base + 2 < n) v2 = cnt[base + 2];
    if (base + 3 < n) v3 = cnt[base + 3];
  }
  int s = v0 + v1 + v2 + v3;
  __shared__ int sh[256];
  sh[t] = s;
  __syncthreads();
  for (int off = 1; off < 256; off <<= 1) {
    int u = (t >= off) ? sh[t - off] : 0;
    __syncthreads();
    sh[t] += u;
    __syncthreads();
  }
  int run = blocksum[blockIdx.x] + sh[t] - s;
  int p0 = run, p1 = run + v0, p2 = p1 + v1, p3 = p2 + v2;
  if (base + 4 <= n) {
    *reinterpret_cast<int4*>(&row_start[base]) = make_int4(p0, p1, p2, p3);
    *reinterpret_cast<int4*>(&cursor[base]) = make_int4(p0, p1, p2, p3);
  } else {
    if (base + 0 < n) { row_start[base + 0] = p0; cursor[base + 0] = p0; }
    if (base + 1 < n) { row_start[base + 1] = p1; cursor[base + 1] = p1; }
    if (base + 2 < n) { row_start[base + 2] = p2; cursor[base + 2] = p2; }
    if (base + 3 < n) { row_start[base + 3] = p3; cursor[base + 3] = p3; }
  }
}

__global__ __launch_bounds__(256) void fill_kernel(const int* __restrict__ src,
                                                   const int* __restrict__ dst,
                                                   int* __restrict__ cursor,
                                                   int* __restrict__ ssrc, int E) {
  int i = blockIdx.x * 256 + threadIdx.x;
  if (i < E) {
    int p = atomicAdd(&cursor[dst[i]], 1);
    ssrc[p] = src[i];
  }
}

// ---- LDS-tiled fp32 GEMM: G[r][c] = (X[r][:] . W[:][c]) * dinv[r] ----
// Tile: RPB rows x Cp cols, 256 threads, each thread a 4x4 register block.
// Xs rows padded +4 floats so compute-loop reads are <=2-way bank-aliased (free).
template <int K, int C>
__global__ __launch_bounds__(256) void gemm_scale_kernel(const float* __restrict__ X,
                                                         const float* __restrict__ W,
                                                         const float* __restrict__ dinv,
                                                         float* __restrict__ G, int n) {
  constexpr int Cp = ((C + 63) / 64) * 64;  // 64 or 128
  constexpr int CQ = Cp / 4;                // col-quads: 16 or 32
  constexpr int RG = 256 / CQ;              // row-groups: 16 or 8
  constexpr int RPB = RG * 4;               // rows per block: 64 or 32
  constexpr int XPITCH = K + 4;             // bank-offset pad, keeps 16B align
  constexpr int TPR = 256 / RPB;            // staging threads per row: 4 or 8

  __shared__ float Xs[RPB * XPITCH];
  __shared__ float Ws[K * Cp];

  const int tid = threadIdx.x;
  const int rbase = blockIdx.x * RPB;

  // stage W (zero-fill padded cols)
  if (C == Cp) {
    for (int i = tid; i < K * C / 4; i += 256)
      reinterpret_cast<float4*>(Ws)[i] = reinterpret_cast<const float4*>(W)[i];
  } else {
    for (int i = tid; i < K * CQ; i += 256) {
      int k = i / CQ, cq = i % CQ, c = cq * 4;
      float4 v = make_float4(0.f, 0.f, 0.f, 0.f);
      if (c < C) v = *reinterpret_cast<const float4*>(&W[k * C + c]);  // C%4==0
      reinterpret_cast<float4*>(&Ws[k * Cp])[cq] = v;
    }
  }
  // stage X tile (row-clamped for tail block; stores are guarded later)
  {
    int r = tid / TPR, j = tid % TPR;
    int grow = rbase + r;
    if (grow >= n) grow = n - 1;
    const float4* xr = reinterpret_cast<const float4*>(&X[(size_t)grow * K]);
    float4* xd = reinterpret_cast<float4*>(&Xs[r * XPITCH]);
#pragma unroll
    for (int it = 0; it < K / 4 / TPR; ++it) xd[j + it * TPR] = xr[j + it * TPR];
  }
  __syncthreads();

  const int ct = tid % CQ, rt = tid / CQ;
  const int c0 = ct * 4, r0 = rt * 4;

  float acc[4][4];
#pragma unroll
  for (int a = 0; a < 4; ++a)
#pragma unroll
    for (int b = 0; b < 4; ++b) acc[a][b] = 0.f;

  for (int k = 0; k < K; k += 4) {
    float4 w0 = *reinterpret_cast<const float4*>(&Ws[(k + 0) * Cp + c0]);
    float4 w1 = *reinterpret_cast<const float4*>(&Ws[(k + 1) * Cp + c0]);
    float4 w2 = *reinterpret_cast<const float4*>(&Ws[(k + 2) * Cp + c0]);
    float4 w3 = *reinterpret_cast<const float4*>(&Ws[(k + 3) * Cp + c0]);
#pragma unroll
    for (int rr = 0; rr < 4; ++rr) {
      float4 xv = *reinterpret_cast<const float4*>(&Xs[(r0 + rr) * XPITCH + k]);
      acc[rr][0] = fmaf(xv.w, w3.x, fmaf(xv.z, w2.x, fmaf(xv.y, w1.x, fmaf(xv.x, w0.x, acc[rr][0]))));
      acc[rr][1] = fmaf(xv.w, w3.y, fmaf(xv.z, w2.y, fmaf(xv.y, w1.y, fmaf(xv.x, w0.y, acc[rr][1]))));
      acc[rr][2] = fmaf(xv.w, w3.z, fmaf(xv.z, w2.z, fmaf(xv.y, w1.z, fmaf(xv.x, w0.z, acc[rr][2]))));
      acc[rr][3] = fmaf(xv.w, w3.w, fmaf(xv.z, w2.w, fmaf(xv.y, w1.w, fmaf(xv.x, w0.w, acc[rr][3]))));
    }
  }

#pragma unroll
  for (int rr = 0; rr < 4; ++rr) {
    int row = rbase + r0 + rr;
    if (row < n && c0 < C) {
      float di = dinv[row];
      float4 v = make_float4(acc[rr][0] * di, acc[rr][1] * di, acc[rr][2] * di, acc[rr][3] * di);
      *reinterpret_cast<float4*>(&G[(size_t)row * C + c0]) = v;  // C%4==0, c0+4<=C when c0<C
    }
  }
}

// out[d][c] = [relu]( dinv[d]*(g[d][c] + sum_{e in row d} g[ssrc[e]][c]) + bias[c] )
template <int C, bool RELU>
__global__ __launch_bounds__(256) void agg_kernel(const float* __restrict__ g,
                                                  const int* __restrict__ row_start,
                                                  const int* __restrict__ ssrc,
                                                  const float* __restrict__ dinv,
                                                  const float* __restrict__ bias,
                                                  float* __restrict__ out, int n) {
  constexpr int TPN = (C <= 64) ? 64 : 128;  // threads per node
  constexpr int NPB = 256 / TPN;             // nodes per block
  int local = threadIdx.x / TPN;
  int c = threadIdx.x % TPN;
  int node = blockIdx.x * NPB + local;
  if (node >= n || c >= C) return;
  int e0 = row_start[node];
  int e1 = row_start[node + 1];
  float acc = g[(size_t)node * C + c];       // self-loop term
  int e = e0;
  for (; e + 3 < e1; e += 4) {
    int s0 = ssrc[e + 0], s1 = ssrc[e + 1], s2 = ssrc[e + 2], s3 = ssrc[e + 3];
    float v0 = g[(size_t)s0 * C + c];
    float v1 = g[(size_t)s1 * C + c];
    float v2 = g[(size_t)s2 * C + c];
    float v3 = g[(size_t)s3 * C + c];
    acc += v0; acc += v1; acc += v2; acc += v3;
  }
  for (; e < e1; ++e) acc += g[(size_t)ssrc[e] * C + c];
  float r = acc * dinv[node] + bias[c];
  if (RELU) r = fmaxf(r, 0.f);
  out[(size_t)node * C + c] = r;
}

extern "C" void kernel_launch(void* const* d_in, const int* in_sizes, int n_in,
                              void* d_out, int out_size, void* d_ws, size_t ws_size,
                              hipStream_t stream) {
  const float* x = (const float*)d_in[0];
  const int* ei = (const int*)d_in[1];
  const float* W1 = (const float*)d_in[2];
  const float* b1 = (const float*)d_in[3];
  const float* W2 = (const float*)d_in[4];
  const float* b2 = (const float*)d_in[5];
  const float* W3 = (const float*)d_in[6];
  const float* b3 = (const float*)d_in[7];
  float* out = (float*)d_out;

  const int n = in_sizes[0] / IN_DIM;  // 100000
  const int E = in_sizes[1] / 2;       // 1600000
  const int* src = ei;
  const int* dst = ei + E;

  char* p = (char*)d_ws;
  auto alloc = [&](size_t bytes) {
    char* q = p;
    p += (bytes + 255) & ~(size_t)255;
    return q;
  };
  float* dinv = (float*)alloc((size_t)n * 4);
  int* row_start = (int*)alloc((size_t)(n + 1) * 4);
  int* cursor = (int*)alloc((size_t)n * 4);      // doubles as cnt
  int* blocksum = (int*)alloc((size_t)1024 * 4);
  int* ssrc = (int*)alloc((size_t)E * 4);
  float* bufG = (float*)alloc((size_t)n * OUT_DIM * 4);  // max cols = 112
  float* bufH = (float*)alloc((size_t)n * HID * 4);

  const int NB = (n + SCAN_TILE - 1) / SCAN_TILE;  // 98 for n=100000

  // ---- CSR build (once; shared by all 3 layers) ----
  hipMemsetAsync(cursor, 0, (size_t)n * 4, stream);
  count_kernel<<<(E + 255) / 256, 256, 0, stream>>>(dst, cursor, E);
  dinv_kernel<<<(n + 255) / 256, 256, 0, stream>>>(cursor, dinv, n);
  scan_partial_kernel<<<NB, 256, 0, stream>>>(cursor, blocksum, n);
  scan_blocksums_kernel<<<1, 1024, 0, stream>>>(blocksum, &row_start[n], NB);
  scan_final_kernel<<<NB, 256, 0, stream>>>(cursor, blocksum, row_start, cursor, n);
  fill_kernel<<<(E + 255) / 256, 256, 0, stream>>>(src, dst, cursor, ssrc, E);

  // ---- layer 1: 128 -> 64, relu ----
  gemm_scale_kernel<IN_DIM, HID><<<(n + 63) / 64, 256, 0, stream>>>(x, W1, dinv, bufG, n);
  agg_kernel<HID, true><<<(n + 3) / 4, 256, 0, stream>>>(bufG, row_start, ssrc, dinv, b1, bufH, n);

  // ---- layer 2: 64 -> 64, relu ----
  gemm_scale_kernel<HID, HID><<<(n + 63) / 64, 256, 0, stream>>>(bufH, W2, dinv, bufG, n);
  agg_kernel<HID, true><<<(n + 3) / 4, 256, 0, stream>>>(bufG, row_start, ssrc, dinv, b2, bufH, n);

  // ---- layer 3: 64 -> 112, no relu ----
  gemm_scale_kernel<HID, OUT_DIM><<<(n + 31) / 32, 256, 0, stream>>>(bufH, W3, dinv, bufG, n);
  agg_kernel<OUT_DIM, false><<<(n + 1) / 2, 256, 0, stream>>>(bufG, row_start, ssrc, dinv, b3, out, n);
}

// Round 4
// 672.484 us; speedup vs baseline: 1.6764x; 1.0737x over previous
//
#include <hip/hip_runtime.h>
#include <math.h>

// GCN 3-layer: out[d] = dinv[d]*(sum_{s->d} g[s] + g[d]) + b,  g = (x@W)*dinv[row]
// CSR built once per launch via L2-friendly 2-phase bucket sort.

#define IN_DIM 128
#define HID 64
#define OUT_DIM 112
#define SCAN_TILE 1024   // elems per node-scan block: 256 threads x 4
#define BSHIFT 5         // 32 nodes per bucket
#define BMASK 31
#define MAX_BUCKETS 4096 // supports n <= 131072

// ---- bucket pass A: count edges per bucket (LDS histogram) ----
__global__ __launch_bounds__(256) void bucket_count_kernel(const int* __restrict__ dst,
                                                           int* __restrict__ bcnt,
                                                           int E, int nb) {
  __shared__ int hist[MAX_BUCKETS];
  for (int i = threadIdx.x; i < nb; i += 256) hist[i] = 0;
  __syncthreads();
  int stride = gridDim.x * 256;
  for (int i = blockIdx.x * 256 + threadIdx.x; i < E; i += stride)
    atomicAdd(&hist[dst[i] >> BSHIFT], 1);
  __syncthreads();
  for (int i = threadIdx.x; i < nb; i += 256)
    if (hist[i]) atomicAdd(&bcnt[i], hist[i]);
}

// exclusive scan of bucket counts (single block, nb <= 4096).
// writes compact bbase[0..nb] and line-padded cursors bcur[i*16].
__global__ __launch_bounds__(1024) void scan_buckets_kernel(const int* __restrict__ bcnt,
                                                            int* __restrict__ bbase,
                                                            int* __restrict__ bcur, int nb) {
  __shared__ int sh[1024];
  int t = threadIdx.x;
  int base = t * 4;
  int v0 = 0, v1 = 0, v2 = 0, v3 = 0;
  if (base + 0 < nb) v0 = bcnt[base + 0];
  if (base + 1 < nb) v1 = bcnt[base + 1];
  if (base + 2 < nb) v2 = bcnt[base + 2];
  if (base + 3 < nb) v3 = bcnt[base + 3];
  int s = v0 + v1 + v2 + v3;
  sh[t] = s;
  __syncthreads();
  for (int off = 1; off < 1024; off <<= 1) {
    int u = (t >= off) ? sh[t - off] : 0;
    __syncthreads();
    sh[t] += u;
    __syncthreads();
  }
  int run = sh[t] - s;
  int p0 = run, p1 = run + v0, p2 = p1 + v1, p3 = p2 + v2;
  if (base + 0 < nb) { bbase[base + 0] = p0; bcur[(base + 0) * 16] = p0; }
  if (base + 1 < nb) { bbase[base + 1] = p1; bcur[(base + 1) * 16] = p1; }
  if (base + 2 < nb) { bbase[base + 2] = p2; bcur[(base + 2) * 16] = p2; }
  if (base + 3 < nb) { bbase[base + 3] = p3; bcur[(base + 3) * 16] = p3; }
  if (t == 0) bbase[nb] = sh[1023];
}

// scatter edges into bucket regions as packed (src<<5 | dst&31)
__global__ __launch_bounds__(256) void bucket_scatter_kernel(const int* __restrict__ src,
                                                             const int* __restrict__ dst,
                                                             int* __restrict__ bcur,
                                                             int* __restrict__ packed, int E) {
  int i = blockIdx.x * 256 + threadIdx.x;
  if (i < E) {
    int s = src[i], d = dst[i];
    int b = d >> BSHIFT;
    int pos = atomicAdd(&bcur[b * 16], 1);
    packed[pos] = (s << BSHIFT) | (d & BMASK);
  }
}

// per-bucket node-degree histogram -> cnt (sequential stores)
__global__ __launch_bounds__(128) void bucket_node_count_kernel(const int* __restrict__ packed,
                                                                const int* __restrict__ bbase,
                                                                int* __restrict__ cnt, int n) {
  int b = blockIdx.x;
  __shared__ int hist[32];
  int t = threadIdx.x;
  if (t < 32) hist[t] = 0;
  __syncthreads();
  int e0 = bbase[b], e1 = bbase[b + 1];
  for (int e = e0 + t; e < e1; e += 128) atomicAdd(&hist[packed[e] & BMASK], 1);
  __syncthreads();
  int node = b * 32 + t;
  if (t < 32 && node < n) cnt[node] = hist[t];
}

// per-bucket fill of ssrc using LDS cursors (writes land in ~deg*32*4B contiguous region)
__global__ __launch_bounds__(128) void fill_from_buckets_kernel(const int* __restrict__ packed,
                                                                const int* __restrict__ bbase,
                                                                const int* __restrict__ row_start,
                                                                int* __restrict__ ssrc, int n) {
  int b = blockIdx.x;
  __shared__ int cur[32];
  int t = threadIdx.x;
  if (t < 32) {
    int node = b * 32 + t;
    cur[t] = (node < n) ? row_start[node] : 0;
  }
  __syncthreads();
  int e0 = bbase[b], e1 = bbase[b + 1];
  for (int e = e0 + t; e < e1; e += 128) {
    int p = packed[e];
    int slot = atomicAdd(&cur[p & BMASK], 1);
    ssrc[slot] = p >> BSHIFT;
  }
}

__global__ __launch_bounds__(256) void dinv_kernel(const int* __restrict__ cnt,
                                                   float* __restrict__ dinv, int n) {
  int i = blockIdx.x * 256 + threadIdx.x;
  if (i < n) dinv[i] = 1.0f / sqrtf((float)(cnt[i] + 1));  // +1 = self loop
}

// ---- hierarchical exclusive scan over node counts -> row_start ----

__global__ __launch_bounds__(256) void scan_partial_kernel(const int* __restrict__ cnt,
                                                           int* __restrict__ blocksum,
                                                           int n) {
  int t = threadIdx.x;
  int base = blockIdx.x * SCAN_TILE + t * 4;
  int s = 0;
  if (base + 4 <= n) {
    int4 v = *reinterpret_cast<const int4*>(&cnt[base]);
    s = v.x + v.y + v.z + v.w;
  } else {
    for (int i = 0; i < 4; ++i)
      if (base + i < n) s += cnt[base + i];
  }
#pragma unroll
  for (int off = 1; off < 64; off <<= 1) s += __shfl_xor(s, off);
  __shared__ int wsum[4];
  int lane = t & 63, wv = t >> 6;
  if (lane == 0) wsum[wv] = s;
  __syncthreads();
  if (t == 0) blocksum[blockIdx.x] = wsum[0] + wsum[1] + wsum[2] + wsum[3];
}

__global__ __launch_bounds__(1024) void scan_blocksums_kernel(int* __restrict__ blocksum,
                                                              int* __restrict__ total_out,
                                                              int nb) {
  __shared__ int sh[1024];
  int t = threadIdx.x;
  int v = (t < nb) ? blocksum[t] : 0;
  sh[t] = v;
  __syncthreads();
  for (int off = 1; off < 1024; off <<= 1) {
    int u = (t >= off) ? sh[t - off] : 0;
    __syncthreads();
    sh[t] += u;
    __syncthreads();
  }
  if (t < nb) blocksum[t] = sh[t] - v;  // exclusive
  if (t == 1023) *total_out = sh[1023]; // grand total
}

__global__ __launch_bounds__(256) void scan_final_kernel(const int* __restrict__ cnt,
                                                         const int* __restrict__ blocksum,
                                                         int* __restrict__ row_start, int n) {
  int t = threadIdx.x;
  int base = blockIdx.x * SCAN_TILE + t * 4;
  int v0 = 0, v1 = 0, v2 = 0, v3 = 0;
  if (base + 4 <= n) {
    int4 v = *reinterpret_cast<const int4*>(&cnt[base]);
    v0 = v.x; v1 = v.y; v2 = v.z; v3 = v.w;
  } else {
    if (base + 0 < n) v0 = cnt[base + 0];
    if (base + 1 < n) v1 = cnt[base + 1];
    if (base + 2 < n) v2 = cnt[base + 2];
    if (base + 3 < n) v3 = cnt[base + 3];
  }
  int s = v0 + v1 + v2 + v3;
  __shared__ int sh[256];
  sh[t] = s;
  __syncthreads();
  for (int off = 1; off < 256; off <<= 1) {
    int u = (t >= off) ? sh[t - off] : 0;
    __syncthreads();
    sh[t] += u;
    __syncthreads();
  }
  int run = blocksum[blockIdx.x] + sh[t] - s;
  int p0 = run, p1 = run + v0, p2 = p1 + v1, p3 = p2 + v2;
  if (base + 4 <= n) {
    *reinterpret_cast<int4*>(&row_start[base]) = make_int4(p0, p1, p2, p3);
  } else {
    if (base + 0 < n) row_start[base + 0] = p0;
    if (base + 1 < n) row_start[base + 1] = p1;
    if (base + 2 < n) row_start[base + 2] = p2;
    if (base + 3 < n) row_start[base + 3] = p3;
  }
}

// ---- LDS-tiled fp32 GEMM: G[r][c] = (X[r][:] . W[:][c]) * dinv[r] ----
template <int K, int C>
__global__ __launch_bounds__(256) void gemm_scale_kernel(const float* __restrict__ X,
                                                         const float* __restrict__ W,
                                                         const float* __restrict__ dinv,
                                                         float* __restrict__ G, int n) {
  constexpr int Cp = ((C + 63) / 64) * 64;  // 64 or 128
  constexpr int CQ = Cp / 4;                // col-quads: 16 or 32
  constexpr int RG = 256 / CQ;              // row-groups: 16 or 8
  constexpr int RPB = RG * 4;               // rows per block: 64 or 32
  constexpr int XPITCH = K + 4;             // bank-offset pad, keeps 16B align
  constexpr int TPR = 256 / RPB;            // staging threads per row: 4 or 8

  __shared__ float Xs[RPB * XPITCH];
  __shared__ float Ws[K * Cp];

  const int tid = threadIdx.x;
  const int rbase = blockIdx.x * RPB;

  if (C == Cp) {
    for (int i = tid; i < K * C / 4; i += 256)
      reinterpret_cast<float4*>(Ws)[i] = reinterpret_cast<const float4*>(W)[i];
  } else {
    for (int i = tid; i < K * CQ; i += 256) {
      int k = i / CQ, cq = i % CQ, c = cq * 4;
      float4 v = make_float4(0.f, 0.f, 0.f, 0.f);
      if (c < C) v = *reinterpret_cast<const float4*>(&W[k * C + c]);  // C%4==0
      reinterpret_cast<float4*>(&Ws[k * Cp])[cq] = v;
    }
  }
  {
    int r = tid / TPR, j = tid % TPR;
    int grow = rbase + r;
    if (grow >= n) grow = n - 1;
    const float4* xr = reinterpret_cast<const float4*>(&X[(size_t)grow * K]);
    float4* xd = reinterpret_cast<float4*>(&Xs[r * XPITCH]);
#pragma unroll
    for (int it = 0; it < K / 4 / TPR; ++it) xd[j + it * TPR] = xr[j + it * TPR];
  }
  __syncthreads();

  const int ct = tid % CQ, rt = tid / CQ;
  const int c0 = ct * 4, r0 = rt * 4;

  float acc[4][4];
#pragma unroll
  for (int a = 0; a < 4; ++a)
#pragma unroll
    for (int b = 0; b < 4; ++b) acc[a][b] = 0.f;

  for (int k = 0; k < K; k += 4) {
    float4 w0 = *reinterpret_cast<const float4*>(&Ws[(k + 0) * Cp + c0]);
    float4 w1 = *reinterpret_cast<const float4*>(&Ws[(k + 1) * Cp + c0]);
    float4 w2 = *reinterpret_cast<const float4*>(&Ws[(k + 2) * Cp + c0]);
    float4 w3 = *reinterpret_cast<const float4*>(&Ws[(k + 3) * Cp + c0]);
#pragma unroll
    for (int rr = 0; rr < 4; ++rr) {
      float4 xv = *reinterpret_cast<const float4*>(&Xs[(r0 + rr) * XPITCH + k]);
      acc[rr][0] = fmaf(xv.w, w3.x, fmaf(xv.z, w2.x, fmaf(xv.y, w1.x, fmaf(xv.x, w0.x, acc[rr][0]))));
      acc[rr][1] = fmaf(xv.w, w3.y, fmaf(xv.z, w2.y, fmaf(xv.y, w1.y, fmaf(xv.x, w0.y, acc[rr][1]))));
      acc[rr][2] = fmaf(xv.w, w3.z, fmaf(xv.z, w2.z, fmaf(xv.y, w1.z, fmaf(xv.x, w0.z, acc[rr][2]))));
      acc[rr][3] = fmaf(xv.w, w3.w, fmaf(xv.z, w2.w, fmaf(xv.y, w1.w, fmaf(xv.x, w0.w, acc[rr][3]))));
    }
  }

#pragma unroll
  for (int rr = 0; rr < 4; ++rr) {
    int row = rbase + r0 + rr;
    if (row < n && c0 < C) {
      float di = dinv[row];
      float4 v = make_float4(acc[rr][0] * di, acc[rr][1] * di, acc[rr][2] * di, acc[rr][3] * di);
      *reinterpret_cast<float4*>(&G[(size_t)row * C + c0]) = v;
    }
  }
}

// out[d][c] = [relu]( dinv[d]*(g[d][c] + sum_{e in row d} g[ssrc[e]][c]) + bias[c] )
template <int C, bool RELU>
__global__ __launch_bounds__(256) void agg_kernel(const float* __restrict__ g,
                                                  const int* __restrict__ row_start,
                                                  const int* __restrict__ ssrc,
                                                  const float* __restrict__ dinv,
                                                  const float* __restrict__ bias,
                                                  float* __restrict__ out, int n) {
  constexpr int TPN = (C <= 64) ? 64 : 128;  // threads per node
  constexpr int NPB = 256 / TPN;             // nodes per block
  int local = threadIdx.x / TPN;
  int c = threadIdx.x % TPN;
  int node = blockIdx.x * NPB + local;
  if (node >= n || c >= C) return;
  int e0 = row_start[node];
  int e1 = row_start[node + 1];
  float acc = g[(size_t)node * C + c];       // self-loop term
  int e = e0;
  for (; e + 7 < e1; e += 8) {
    int s0 = ssrc[e + 0], s1 = ssrc[e + 1], s2 = ssrc[e + 2], s3 = ssrc[e + 3];
    int s4 = ssrc[e + 4], s5 = ssrc[e + 5], s6 = ssrc[e + 6], s7 = ssrc[e + 7];
    float v0 = g[(size_t)s0 * C + c];
    float v1 = g[(size_t)s1 * C + c];
    float v2 = g[(size_t)s2 * C + c];
    float v3 = g[(size_t)s3 * C + c];
    float v4 = g[(size_t)s4 * C + c];
    float v5 = g[(size_t)s5 * C + c];
    float v6 = g[(size_t)s6 * C + c];
    float v7 = g[(size_t)s7 * C + c];
    acc += v0; acc += v1; acc += v2; acc += v3;
    acc += v4; acc += v5; acc += v6; acc += v7;
  }
  for (; e < e1; ++e) acc += g[(size_t)ssrc[e] * C + c];
  float r = acc * dinv[node] + bias[c];
  if (RELU) r = fmaxf(r, 0.f);
  out[(size_t)node * C + c] = r;
}

extern "C" void kernel_launch(void* const* d_in, const int* in_sizes, int n_in,
                              void* d_out, int out_size, void* d_ws, size_t ws_size,
                              hipStream_t stream) {
  const float* x = (const float*)d_in[0];
  const int* ei = (const int*)d_in[1];
  const float* W1 = (const float*)d_in[2];
  const float* b1 = (const float*)d_in[3];
  const float* W2 = (const float*)d_in[4];
  const float* b2 = (const float*)d_in[5];
  const float* W3 = (const float*)d_in[6];
  const float* b3 = (const float*)d_in[7];
  float* out = (float*)d_out;

  const int n = in_sizes[0] / IN_DIM;  // 100000
  const int E = in_sizes[1] / 2;       // 1600000
  const int* src = ei;
  const int* dst = ei + E;
  const int nbuck = (n + BMASK) >> BSHIFT;  // 3125

  char* p = (char*)d_ws;
  auto alloc = [&](size_t bytes) {
    char* q = p;
    p += (bytes + 255) & ~(size_t)255;
    return q;
  };
  float* dinv = (float*)alloc((size_t)n * 4);
  int* row_start = (int*)alloc((size_t)(n + 1) * 4);
  int* cnt = (int*)alloc((size_t)n * 4);
  int* blocksum = (int*)alloc((size_t)1024 * 4);
  int* bcnt = (int*)alloc((size_t)MAX_BUCKETS * 4);
  int* bbase = (int*)alloc((size_t)(MAX_BUCKETS + 1) * 4);
  int* bcur = (int*)alloc((size_t)MAX_BUCKETS * 16 * 4);  // line-padded cursors
  int* packed = (int*)alloc((size_t)E * 4);
  int* ssrc = (int*)alloc((size_t)E * 4);
  float* bufG = (float*)alloc((size_t)n * OUT_DIM * 4);  // max cols = 112
  float* bufH = (float*)alloc((size_t)n * HID * 4);

  const int NB = (n + SCAN_TILE - 1) / SCAN_TILE;  // 98 node-scan blocks

  // ---- CSR build via bucket sort (once; shared by all 3 layers) ----
  hipMemsetAsync(bcnt, 0, (size_t)nbuck * 4, stream);
  bucket_count_kernel<<<64, 256, 0, stream>>>(dst, bcnt, E, nbuck);
  scan_buckets_kernel<<<1, 1024, 0, stream>>>(bcnt, bbase, bcur, nbuck);
  bucket_scatter_kernel<<<(E + 255) / 256, 256, 0, stream>>>(src, dst, bcur, packed, E);
  bucket_node_count_kernel<<<nbuck, 128, 0, stream>>>(packed, bbase, cnt, n);
  dinv_kernel<<<(n + 255) / 256, 256, 0, stream>>>(cnt, dinv, n);
  scan_partial_kernel<<<NB, 256, 0, stream>>>(cnt, blocksum, n);
  scan_blocksums_kernel<<<1, 1024, 0, stream>>>(blocksum, &row_start[n], NB);
  scan_final_kernel<<<NB, 256, 0, stream>>>(cnt, blocksum, row_start, n);
  fill_from_buckets_kernel<<<nbuck, 128, 0, stream>>>(packed, bbase, row_start, ssrc, n);

  // ---- layer 1: 128 -> 64, relu ----
  gemm_scale_kernel<IN_DIM, HID><<<(n + 63) / 64, 256, 0, stream>>>(x, W1, dinv, bufG, n);
  agg_kernel<HID, true><<<(n + 3) / 4, 256, 0, stream>>>(bufG, row_start, ssrc, dinv, b1, bufH, n);

  // ---- layer 2: 64 -> 64, relu ----
  gemm_scale_kernel<HID, HID><<<(n + 63) / 64, 256, 0, stream>>>(bufH, W2, dinv, bufG, n);
  agg_kernel<HID, true><<<(n + 3) / 4, 256, 0, stream>>>(bufG, row_start, ssrc, dinv, b2, bufH, n);

  // ---- layer 3: 64 -> 112, no relu ----
  gemm_scale_kernel<HID, OUT_DIM><<<(n + 31) / 32, 256, 0, stream>>>(bufH, W3, dinv, bufG, n);
  agg_kernel<OUT_DIM, false><<<(n + 1) / 2, 256, 0, stream>>>(bufG, row_start, ssrc, dinv, b3, out, n);
}

// Round 5
// 572.947 us; speedup vs baseline: 1.9677x; 1.1737x over previous
//
#include <hip/hip_runtime.h>
#include <math.h>

// GCN 3-layer: out = Â relu(Â relu(Â x W1 + b1) W2 + b2) W3 + b3, Â = D^-1/2(A+I)D^-1/2
// Layer 3 reordered: Â(h2 W3) = (Â h2) W3  -> aggregate in 64-dim, then GEMM 64->112.
// CSR built once per launch via L2-friendly 2-phase bucket sort.

#define IN_DIM 128
#define HID 64
#define OUT_DIM 112
#define SCAN_TILE 1024   // elems per node-scan block: 256 threads x 4
#define BSHIFT 5         // 32 nodes per bucket
#define BMASK 31
#define MAX_BUCKETS 4096 // supports n <= 131072

// ---- bucket pass A: count edges per bucket (LDS histogram) ----
__global__ __launch_bounds__(256) void bucket_count_kernel(const int* __restrict__ dst,
                                                           int* __restrict__ bcnt,
                                                           int E, int nb) {
  __shared__ int hist[MAX_BUCKETS];
  for (int i = threadIdx.x; i < nb; i += 256) hist[i] = 0;
  __syncthreads();
  int stride = gridDim.x * 256;
  for (int i = blockIdx.x * 256 + threadIdx.x; i < E; i += stride)
    atomicAdd(&hist[dst[i] >> BSHIFT], 1);
  __syncthreads();
  for (int i = threadIdx.x; i < nb; i += 256)
    if (hist[i]) atomicAdd(&bcnt[i], hist[i]);
}

// exclusive scan of bucket counts (single block, nb <= 4096).
__global__ __launch_bounds__(1024) void scan_buckets_kernel(const int* __restrict__ bcnt,
                                                            int* __restrict__ bbase,
                                                            int* __restrict__ bcur, int nb) {
  __shared__ int sh[1024];
  int t = threadIdx.x;
  int base = t * 4;
  int v0 = 0, v1 = 0, v2 = 0, v3 = 0;
  if (base + 0 < nb) v0 = bcnt[base + 0];
  if (base + 1 < nb) v1 = bcnt[base + 1];
  if (base + 2 < nb) v2 = bcnt[base + 2];
  if (base + 3 < nb) v3 = bcnt[base + 3];
  int s = v0 + v1 + v2 + v3;
  sh[t] = s;
  __syncthreads();
  for (int off = 1; off < 1024; off <<= 1) {
    int u = (t >= off) ? sh[t - off] : 0;
    __syncthreads();
    sh[t] += u;
    __syncthreads();
  }
  int run = sh[t] - s;
  int p0 = run, p1 = run + v0, p2 = p1 + v1, p3 = p2 + v2;
  if (base + 0 < nb) { bbase[base + 0] = p0; bcur[(base + 0) * 16] = p0; }
  if (base + 1 < nb) { bbase[base + 1] = p1; bcur[(base + 1) * 16] = p1; }
  if (base + 2 < nb) { bbase[base + 2] = p2; bcur[(base + 2) * 16] = p2; }
  if (base + 3 < nb) { bbase[base + 3] = p3; bcur[(base + 3) * 16] = p3; }
  if (t == 0) bbase[nb] = sh[1023];
}

// scatter edges into bucket regions as packed (src<<5 | dst&31)
__global__ __launch_bounds__(256) void bucket_scatter_kernel(const int* __restrict__ src,
                                                             const int* __restrict__ dst,
                                                             int* __restrict__ bcur,
                                                             int* __restrict__ packed, int E) {
  int i = blockIdx.x * 256 + threadIdx.x;
  if (i < E) {
    int s = src[i], d = dst[i];
    int b = d >> BSHIFT;
    int pos = atomicAdd(&bcur[b * 16], 1);
    packed[pos] = (s << BSHIFT) | (d & BMASK);
  }
}

// per-bucket node-degree histogram -> cnt (sequential stores)
__global__ __launch_bounds__(128) void bucket_node_count_kernel(const int* __restrict__ packed,
                                                                const int* __restrict__ bbase,
                                                                int* __restrict__ cnt, int n) {
  int b = blockIdx.x;
  __shared__ int hist[32];
  int t = threadIdx.x;
  if (t < 32) hist[t] = 0;
  __syncthreads();
  int e0 = bbase[b], e1 = bbase[b + 1];
  for (int e = e0 + t; e < e1; e += 128) atomicAdd(&hist[packed[e] & BMASK], 1);
  __syncthreads();
  int node = b * 32 + t;
  if (t < 32 && node < n) cnt[node] = hist[t];
}

// per-bucket fill of ssrc using LDS cursors
__global__ __launch_bounds__(128) void fill_from_buckets_kernel(const int* __restrict__ packed,
                                                                const int* __restrict__ bbase,
                                                                const int* __restrict__ row_start,
                                                                int* __restrict__ ssrc, int n) {
  int b = blockIdx.x;
  __shared__ int cur[32];
  int t = threadIdx.x;
  if (t < 32) {
    int node = b * 32 + t;
    cur[t] = (node < n) ? row_start[node] : 0;
  }
  __syncthreads();
  int e0 = bbase[b], e1 = bbase[b + 1];
  for (int e = e0 + t; e < e1; e += 128) {
    int p = packed[e];
    int slot = atomicAdd(&cur[p & BMASK], 1);
    ssrc[slot] = p >> BSHIFT;
  }
}

__global__ __launch_bounds__(256) void dinv_kernel(const int* __restrict__ cnt,
                                                   float* __restrict__ dinv, int n) {
  int i = blockIdx.x * 256 + threadIdx.x;
  if (i < n) dinv[i] = 1.0f / sqrtf((float)(cnt[i] + 1));  // +1 = self loop
}

// ---- hierarchical exclusive scan over node counts -> row_start ----

__global__ __launch_bounds__(256) void scan_partial_kernel(const int* __restrict__ cnt,
                                                           int* __restrict__ blocksum,
                                                           int n) {
  int t = threadIdx.x;
  int base = blockIdx.x * SCAN_TILE + t * 4;
  int s = 0;
  if (base + 4 <= n) {
    int4 v = *reinterpret_cast<const int4*>(&cnt[base]);
    s = v.x + v.y + v.z + v.w;
  } else {
    for (int i = 0; i < 4; ++i)
      if (base + i < n) s += cnt[base + i];
  }
#pragma unroll
  for (int off = 1; off < 64; off <<= 1) s += __shfl_xor(s, off);
  __shared__ int wsum[4];
  int lane = t & 63, wv = t >> 6;
  if (lane == 0) wsum[wv] = s;
  __syncthreads();
  if (t == 0) blocksum[blockIdx.x] = wsum[0] + wsum[1] + wsum[2] + wsum[3];
}

__global__ __launch_bounds__(1024) void scan_blocksums_kernel(int* __restrict__ blocksum,
                                                              int* __restrict__ total_out,
                                                              int nb) {
  __shared__ int sh[1024];
  int t = threadIdx.x;
  int v = (t < nb) ? blocksum[t] : 0;
  sh[t] = v;
  __syncthreads();
  for (int off = 1; off < 1024; off <<= 1) {
    int u = (t >= off) ? sh[t - off] : 0;
    __syncthreads();
    sh[t] += u;
    __syncthreads();
  }
  if (t < nb) blocksum[t] = sh[t] - v;  // exclusive
  if (t == 1023) *total_out = sh[1023]; // grand total
}

__global__ __launch_bounds__(256) void scan_final_kernel(const int* __restrict__ cnt,
                                                         const int* __restrict__ blocksum,
                                                         int* __restrict__ row_start, int n) {
  int t = threadIdx.x;
  int base = blockIdx.x * SCAN_TILE + t * 4;
  int v0 = 0, v1 = 0, v2 = 0, v3 = 0;
  if (base + 4 <= n) {
    int4 v = *reinterpret_cast<const int4*>(&cnt[base]);
    v0 = v.x; v1 = v.y; v2 = v.z; v3 = v.w;
  } else {
    if (base + 0 < n) v0 = cnt[base + 0];
    if (base + 1 < n) v1 = cnt[base + 1];
    if (base + 2 < n) v2 = cnt[base + 2];
    if (base + 3 < n) v3 = cnt[base + 3];
  }
  int s = v0 + v1 + v2 + v3;
  __shared__ int sh[256];
  sh[t] = s;
  __syncthreads();
  for (int off = 1; off < 256; off <<= 1) {
    int u = (t >= off) ? sh[t - off] : 0;
    __syncthreads();
    sh[t] += u;
    __syncthreads();
  }
  int run = blocksum[blockIdx.x] + sh[t] - s;
  int p0 = run, p1 = run + v0, p2 = p1 + v1, p3 = p2 + v2;
  if (base + 4 <= n) {
    *reinterpret_cast<int4*>(&row_start[base]) = make_int4(p0, p1, p2, p3);
  } else {
    if (base + 0 < n) row_start[base + 0] = p0;
    if (base + 1 < n) row_start[base + 1] = p1;
    if (base + 2 < n) row_start[base + 2] = p2;
    if (base + 3 < n) row_start[base + 3] = p3;
  }
}

// ---- LDS-tiled fp32 GEMM: G[r][c] = (X[r][:].W[:][c]) * (DINV?dinv[r]:1) + (BIAS?bias[c]:0)
template <int K, int C, bool DINV, bool BIAS>
__global__ __launch_bounds__(256) void gemm_scale_kernel(const float* __restrict__ X,
                                                         const float* __restrict__ W,
                                                         const float* __restrict__ dinv,
                                                         const float* __restrict__ bias,
                                                         float* __restrict__ G, int n) {
  constexpr int Cp = ((C + 63) / 64) * 64;  // 64 or 128
  constexpr int CQ = Cp / 4;                // col-quads: 16 or 32
  constexpr int RG = 256 / CQ;              // row-groups: 16 or 8
  constexpr int RPB = RG * 4;               // rows per block: 64 or 32
  constexpr int XPITCH = K + 4;             // bank-offset pad, keeps 16B align
  constexpr int TPR = 256 / RPB;            // staging threads per row: 4 or 8

  __shared__ float Xs[RPB * XPITCH];
  __shared__ float Ws[K * Cp];

  const int tid = threadIdx.x;
  const int rbase = blockIdx.x * RPB;

  if (C == Cp) {
    for (int i = tid; i < K * C / 4; i += 256)
      reinterpret_cast<float4*>(Ws)[i] = reinterpret_cast<const float4*>(W)[i];
  } else {
    for (int i = tid; i < K * CQ; i += 256) {
      int k = i / CQ, cq = i % CQ, c = cq * 4;
      float4 v = make_float4(0.f, 0.f, 0.f, 0.f);
      if (c < C) v = *reinterpret_cast<const float4*>(&W[k * C + c]);  // C%4==0
      reinterpret_cast<float4*>(&Ws[k * Cp])[cq] = v;
    }
  }
  {
    int r = tid / TPR, j = tid % TPR;
    int grow = rbase + r;
    if (grow >= n) grow = n - 1;
    const float4* xr = reinterpret_cast<const float4*>(&X[(size_t)grow * K]);
    float4* xd = reinterpret_cast<float4*>(&Xs[r * XPITCH]);
#pragma unroll
    for (int it = 0; it < K / 4 / TPR; ++it) xd[j + it * TPR] = xr[j + it * TPR];
  }
  __syncthreads();

  const int ct = tid % CQ, rt = tid / CQ;
  const int c0 = ct * 4, r0 = rt * 4;

  float acc[4][4];
#pragma unroll
  for (int a = 0; a < 4; ++a)
#pragma unroll
    for (int b = 0; b < 4; ++b) acc[a][b] = 0.f;

  for (int k = 0; k < K; k += 4) {
    float4 w0 = *reinterpret_cast<const float4*>(&Ws[(k + 0) * Cp + c0]);
    float4 w1 = *reinterpret_cast<const float4*>(&Ws[(k + 1) * Cp + c0]);
    float4 w2 = *reinterpret_cast<const float4*>(&Ws[(k + 2) * Cp + c0]);
    float4 w3 = *reinterpret_cast<const float4*>(&Ws[(k + 3) * Cp + c0]);
#pragma unroll
    for (int rr = 0; rr < 4; ++rr) {
      float4 xv = *reinterpret_cast<const float4*>(&Xs[(r0 + rr) * XPITCH + k]);
      acc[rr][0] = fmaf(xv.w, w3.x, fmaf(xv.z, w2.x, fmaf(xv.y, w1.x, fmaf(xv.x, w0.x, acc[rr][0]))));
      acc[rr][1] = fmaf(xv.w, w3.y, fmaf(xv.z, w2.y, fmaf(xv.y, w1.y, fmaf(xv.x, w0.y, acc[rr][1]))));
      acc[rr][2] = fmaf(xv.w, w3.z, fmaf(xv.z, w2.z, fmaf(xv.y, w1.z, fmaf(xv.x, w0.z, acc[rr][2]))));
      acc[rr][3] = fmaf(xv.w, w3.w, fmaf(xv.z, w2.w, fmaf(xv.y, w1.w, fmaf(xv.x, w0.w, acc[rr][3]))));
    }
  }

#pragma unroll
  for (int rr = 0; rr < 4; ++rr) {
    int row = rbase + r0 + rr;
    if (row < n && c0 < C) {
      float s = DINV ? dinv[row] : 1.0f;
      float4 v;
      v.x = acc[rr][0] * s;
      v.y = acc[rr][1] * s;
      v.z = acc[rr][2] * s;
      v.w = acc[rr][3] * s;
      if (BIAS) {
        float4 bv = *reinterpret_cast<const float4*>(&bias[c0]);
        v.x += bv.x; v.y += bv.y; v.z += bv.z; v.w += bv.w;
      }
      *reinterpret_cast<float4*>(&G[(size_t)row * C + c0]) = v;
    }
  }
}

// out[d][c] = post( dinv[d]*(g[d][c] + sum_{e in row d} g[ssrc[e]][c]) [+ bias[c]] )
// post = relu if RELU; result additionally *dinv[d] if TSCALE (emits t for layer-3 reorder).
template <int C, bool RELU, bool BIAS, bool TSCALE>
__global__ __launch_bounds__(256) void agg_kernel(const float* __restrict__ g,
                                                  const int* __restrict__ row_start,
                                                  const int* __restrict__ ssrc,
                                                  const float* __restrict__ dinv,
                                                  const float* __restrict__ bias,
                                                  float* __restrict__ out, int n) {
  constexpr int TPN = (C <= 64) ? 64 : 128;  // threads per node
  constexpr int NPB = 256 / TPN;             // nodes per block
  int local = threadIdx.x / TPN;
  int c = threadIdx.x % TPN;
  int node = blockIdx.x * NPB + local;
  if (node >= n || c >= C) return;
  int e0 = row_start[node];
  int e1 = row_start[node + 1];
  float acc = g[(size_t)node * C + c];       // self-loop term
  int e = e0;
  for (; e + 15 < e1; e += 16) {             // 16 outstanding gathers (latency hiding)
    int s[16];
#pragma unroll
    for (int i = 0; i < 16; ++i) s[i] = ssrc[e + i];
    float v[16];
#pragma unroll
    for (int i = 0; i < 16; ++i) v[i] = g[(size_t)s[i] * C + c];
#pragma unroll
    for (int i = 0; i < 16; ++i) acc += v[i];
  }
  for (; e + 3 < e1; e += 4) {
    int s0 = ssrc[e + 0], s1 = ssrc[e + 1], s2 = ssrc[e + 2], s3 = ssrc[e + 3];
    float v0 = g[(size_t)s0 * C + c];
    float v1 = g[(size_t)s1 * C + c];
    float v2 = g[(size_t)s2 * C + c];
    float v3 = g[(size_t)s3 * C + c];
    acc += v0; acc += v1; acc += v2; acc += v3;
  }
  for (; e < e1; ++e) acc += g[(size_t)ssrc[e] * C + c];
  float di = dinv[node];
  float r = acc * di;
  if (BIAS) r += bias[c];
  if (RELU) r = fmaxf(r, 0.f);
  if (TSCALE) r *= di;
  out[(size_t)node * C + c] = r;
}

extern "C" void kernel_launch(void* const* d_in, const int* in_sizes, int n_in,
                              void* d_out, int out_size, void* d_ws, size_t ws_size,
                              hipStream_t stream) {
  const float* x = (const float*)d_in[0];
  const int* ei = (const int*)d_in[1];
  const float* W1 = (const float*)d_in[2];
  const float* b1 = (const float*)d_in[3];
  const float* W2 = (const float*)d_in[4];
  const float* b2 = (const float*)d_in[5];
  const float* W3 = (const float*)d_in[6];
  const float* b3 = (const float*)d_in[7];
  float* out = (float*)d_out;

  const int n = in_sizes[0] / IN_DIM;  // 100000
  const int E = in_sizes[1] / 2;       // 1600000
  const int* src = ei;
  const int* dst = ei + E;
  const int nbuck = (n + BMASK) >> BSHIFT;  // 3125

  char* p = (char*)d_ws;
  auto alloc = [&](size_t bytes) {
    char* q = p;
    p += (bytes + 255) & ~(size_t)255;
    return q;
  };
  float* dinv = (float*)alloc((size_t)n * 4);
  int* row_start = (int*)alloc((size_t)(n + 1) * 4);
  int* cnt = (int*)alloc((size_t)n * 4);
  int* blocksum = (int*)alloc((size_t)1024 * 4);
  int* bcnt = (int*)alloc((size_t)MAX_BUCKETS * 4);
  int* bbase = (int*)alloc((size_t)(MAX_BUCKETS + 1) * 4);
  int* bcur = (int*)alloc((size_t)MAX_BUCKETS * 16 * 4);  // line-padded cursors
  int* packed = (int*)alloc((size_t)E * 4);
  int* ssrc = (int*)alloc((size_t)E * 4);
  float* bufG = (float*)alloc((size_t)n * HID * 4);
  float* bufH = (float*)alloc((size_t)n * HID * 4);

  const int NB = (n + SCAN_TILE - 1) / SCAN_TILE;  // 98 node-scan blocks

  // ---- CSR build via bucket sort (once; shared by all 3 layers) ----
  hipMemsetAsync(bcnt, 0, (size_t)nbuck * 4, stream);
  bucket_count_kernel<<<64, 256, 0, stream>>>(dst, bcnt, E, nbuck);
  scan_buckets_kernel<<<1, 1024, 0, stream>>>(bcnt, bbase, bcur, nbuck);
  bucket_scatter_kernel<<<(E + 255) / 256, 256, 0, stream>>>(src, dst, bcur, packed, E);
  bucket_node_count_kernel<<<nbuck, 128, 0, stream>>>(packed, bbase, cnt, n);
  dinv_kernel<<<(n + 255) / 256, 256, 0, stream>>>(cnt, dinv, n);
  scan_partial_kernel<<<NB, 256, 0, stream>>>(cnt, blocksum, n);
  scan_blocksums_kernel<<<1, 1024, 0, stream>>>(blocksum, &row_start[n], NB);
  scan_final_kernel<<<NB, 256, 0, stream>>>(cnt, blocksum, row_start, n);
  fill_from_buckets_kernel<<<nbuck, 128, 0, stream>>>(packed, bbase, row_start, ssrc, n);

  // ---- layer 1: g1=(x W1)*dinv_row ; h1=relu(agg*dinv + b1) ----
  gemm_scale_kernel<IN_DIM, HID, true, false><<<(n + 63) / 64, 256, 0, stream>>>(x, W1, dinv, nullptr, bufG, n);
  agg_kernel<HID, true, true, false><<<(n + 3) / 4, 256, 0, stream>>>(bufG, row_start, ssrc, dinv, b1, bufH, n);

  // ---- layer 2: g2=(h1 W2)*dinv_row ; t = relu(agg*dinv + b2) * dinv  (pre-scaled for L3) ----
  gemm_scale_kernel<HID, HID, true, false><<<(n + 63) / 64, 256, 0, stream>>>(bufH, W2, dinv, nullptr, bufG, n);
  agg_kernel<HID, true, true, true><<<(n + 3) / 4, 256, 0, stream>>>(bufG, row_start, ssrc, dinv, b2, bufH, n);

  // ---- layer 3 (reordered): z = dinv*(t + sum t[s]) ; out = z W3 + b3 ----
  agg_kernel<HID, false, false, false><<<(n + 3) / 4, 256, 0, stream>>>(bufH, row_start, ssrc, dinv, nullptr, bufG, n);
  gemm_scale_kernel<HID, OUT_DIM, false, true><<<(n + 31) / 32, 256, 0, stream>>>(bufG, W3, dinv, b3, out, n);
}

// Round 6
// 572.595 us; speedup vs baseline: 1.9689x; 1.0006x over previous
//
#include <hip/hip_runtime.h>
#include <math.h>

// GCN 3-layer: out = Â relu(Â relu(Â x W1 + b1) W2 + b2) W3 + b3, Â = D^-1/2(A+I)D^-1/2
// Layer 3 reordered: Â(h2 W3) = (Â h2) W3  -> aggregate in 64-dim, then GEMM 64->112.
// CSR built once per launch via 2-pass radix sort on dst (write-locality-aware:
// every output cache line is written by exactly one block in one burst).

#define IN_DIM 128
#define HID 64
#define OUT_DIM 112
#define SCAN_TILE 1024   // elems per node-scan block: 256 threads x 4
#define LSHIFT 7         // 128 nodes per fine bucket
#define LMASK 127
#define MAXBUCK 1024     // supports n <= 131072
#define CHUNK 8192       // edges per coarse-pass block

// ---- pass 1a: per-chunk histogram of coarse buckets -> H[chunk*nbuck + b] ----
__global__ __launch_bounds__(256) void coarse_hist_kernel(const int* __restrict__ dst,
                                                          int* __restrict__ H,
                                                          int E, int nbuck) {
  __shared__ int hist[MAXBUCK];
  for (int i = threadIdx.x; i < nbuck; i += 256) hist[i] = 0;
  __syncthreads();
  int lo = blockIdx.x * CHUNK;
  int hi = min(E, lo + CHUNK);
  for (int i = lo + threadIdx.x; i < hi; i += 256)
    atomicAdd(&hist[dst[i] >> LSHIFT], 1);
  __syncthreads();
  int* Hrow = &H[(size_t)blockIdx.x * nbuck];
  for (int i = threadIdx.x; i < nbuck; i += 256) Hrow[i] = hist[i];
}

// ---- pass 1b: column totals of H -> btotal[b] (coalesced: lane=bucket) ----
__global__ __launch_bounds__(256) void btotal_kernel(const int* __restrict__ H,
                                                     int* __restrict__ btotal,
                                                     int nchunk, int nbuck) {
  int b = blockIdx.x * 256 + threadIdx.x;
  if (b >= nbuck) return;
  int s = 0;
  for (int c = 0; c < nchunk; ++c) s += H[(size_t)c * nbuck + b];
  btotal[b] = s;
}

// ---- pass 1c: exclusive scan of btotal -> bbase[0..nbuck] (single block) ----
__global__ __launch_bounds__(1024) void bbase_scan_kernel(const int* __restrict__ btotal,
                                                          int* __restrict__ bbase, int nbuck) {
  __shared__ int sh[1024];
  int t = threadIdx.x;
  int v = (t < nbuck) ? btotal[t] : 0;
  sh[t] = v;
  __syncthreads();
  for (int off = 1; off < 1024; off <<= 1) {
    int u = (t >= off) ? sh[t - off] : 0;
    __syncthreads();
    sh[t] += u;
    __syncthreads();
  }
  if (t < nbuck) bbase[t] = sh[t] - v;
  if (t == 1023) bbase[nbuck] = sh[1023];
}

// ---- pass 1d: H[c][b] <- bbase[b] + prefix over chunks (coalesced) ----
__global__ __launch_bounds__(256) void chunk_offset_kernel(int* __restrict__ H,
                                                           const int* __restrict__ bbase,
                                                           int nchunk, int nbuck) {
  int b = blockIdx.x * 256 + threadIdx.x;
  if (b >= nbuck) return;
  int run = bbase[b];
  for (int c = 0; c < nchunk; ++c) {
    size_t idx = (size_t)c * nbuck + b;
    int tmp = H[idx];
    H[idx] = run;
    run += tmp;
  }
}

// ---- pass 1e: scatter edges into coarse-bucket runs as packed (src<<7 | dst&127) ----
// Each (chunk,bucket) run is contiguous and written by one block => L2-local bursts.
__global__ __launch_bounds__(256) void coarse_scatter_kernel(const int* __restrict__ src,
                                                             const int* __restrict__ dst,
                                                             const int* __restrict__ H,
                                                             int* __restrict__ packed,
                                                             int E, int nbuck) {
  __shared__ int cur[MAXBUCK];
  const int* Hrow = &H[(size_t)blockIdx.x * nbuck];
  for (int i = threadIdx.x; i < nbuck; i += 256) cur[i] = Hrow[i];
  __syncthreads();
  int lo = blockIdx.x * CHUNK;
  int hi = min(E, lo + CHUNK);
  for (int i = lo + threadIdx.x; i < hi; i += 256) {
    int s = src[i], d = dst[i];
    int b = d >> LSHIFT;
    int pos = atomicAdd(&cur[b], 1);
    packed[pos] = (s << LSHIFT) | (d & LMASK);
  }
}

// ---- pass 2a: per-bucket node-degree histogram -> cnt (sequential reads+stores) ----
__global__ __launch_bounds__(256) void fine_count_kernel(const int* __restrict__ packed,
                                                         const int* __restrict__ bbase,
                                                         int* __restrict__ cnt, int n) {
  int b = blockIdx.x;
  __shared__ int hist[128];
  int t = threadIdx.x;
  if (t < 128) hist[t] = 0;
  __syncthreads();
  int e0 = bbase[b], e1 = bbase[b + 1];
  for (int e = e0 + t; e < e1; e += 256) atomicAdd(&hist[packed[e] & LMASK], 1);
  __syncthreads();
  int node = b * 128 + t;
  if (t < 128 && node < n) cnt[node] = hist[t];
}

// ---- pass 2b: per-bucket fill of ssrc (one block owns an ~8KB contiguous region) ----
__global__ __launch_bounds__(256) void fine_scatter_kernel(const int* __restrict__ packed,
                                                           const int* __restrict__ bbase,
                                                           const int* __restrict__ row_start,
                                                           int* __restrict__ ssrc, int n) {
  int b = blockIdx.x;
  __shared__ int cur[128];
  int t = threadIdx.x;
  if (t < 128) {
    int node = b * 128 + t;
    cur[t] = (node < n) ? row_start[node] : 0;
  }
  __syncthreads();
  int e0 = bbase[b], e1 = bbase[b + 1];
  for (int e = e0 + t; e < e1; e += 256) {
    int p = packed[e];
    int slot = atomicAdd(&cur[p & LMASK], 1);
    ssrc[slot] = p >> LSHIFT;
  }
}

__global__ __launch_bounds__(256) void dinv_kernel(const int* __restrict__ cnt,
                                                   float* __restrict__ dinv, int n) {
  int i = blockIdx.x * 256 + threadIdx.x;
  if (i < n) dinv[i] = 1.0f / sqrtf((float)(cnt[i] + 1));  // +1 = self loop
}

// ---- hierarchical exclusive scan over node counts -> row_start ----

__global__ __launch_bounds__(256) void scan_partial_kernel(const int* __restrict__ cnt,
                                                           int* __restrict__ blocksum,
                                                           int n) {
  int t = threadIdx.x;
  int base = blockIdx.x * SCAN_TILE + t * 4;
  int s = 0;
  if (base + 4 <= n) {
    int4 v = *reinterpret_cast<const int4*>(&cnt[base]);
    s = v.x + v.y + v.z + v.w;
  } else {
    for (int i = 0; i < 4; ++i)
      if (base + i < n) s += cnt[base + i];
  }
#pragma unroll
  for (int off = 1; off < 64; off <<= 1) s += __shfl_xor(s, off);
  __shared__ int wsum[4];
  int lane = t & 63, wv = t >> 6;
  if (lane == 0) wsum[wv] = s;
  __syncthreads();
  if (t == 0) blocksum[blockIdx.x] = wsum[0] + wsum[1] + wsum[2] + wsum[3];
}

__global__ __launch_bounds__(1024) void scan_blocksums_kernel(int* __restrict__ blocksum,
                                                              int* __restrict__ total_out,
                                                              int nb) {
  __shared__ int sh[1024];
  int t = threadIdx.x;
  int v = (t < nb) ? blocksum[t] : 0;
  sh[t] = v;
  __syncthreads();
  for (int off = 1; off < 1024; off <<= 1) {
    int u = (t >= off) ? sh[t - off] : 0;
    __syncthreads();
    sh[t] += u;
    __syncthreads();
  }
  if (t < nb) blocksum[t] = sh[t] - v;  // exclusive
  if (t == 1023) *total_out = sh[1023]; // grand total
}

__global__ __launch_bounds__(256) void scan_final_kernel(const int* __restrict__ cnt,
                                                         const int* __restrict__ blocksum,
                                                         int* __restrict__ row_start, int n) {
  int t = threadIdx.x;
  int base = blockIdx.x * SCAN_TILE + t * 4;
  int v0 = 0, v1 = 0, v2 = 0, v3 = 0;
  if (base + 4 <= n) {
    int4 v = *reinterpret_cast<const int4*>(&cnt[base]);
    v0 = v.x; v1 = v.y; v2 = v.z; v3 = v.w;
  } else {
    if (base + 0 < n) v0 = cnt[base + 0];
    if (base + 1 < n) v1 = cnt[base + 1];
    if (base + 2 < n) v2 = cnt[base + 2];
    if (base + 3 < n) v3 = cnt[base + 3];
  }
  int s = v0 + v1 + v2 + v3;
  __shared__ int sh[256];
  sh[t] = s;
  __syncthreads();
  for (int off = 1; off < 256; off <<= 1) {
    int u = (t >= off) ? sh[t - off] : 0;
    __syncthreads();
    sh[t] += u;
    __syncthreads();
  }
  int run = blocksum[blockIdx.x] + sh[t] - s;
  int p0 = run, p1 = run + v0, p2 = p1 + v1, p3 = p2 + v2;
  if (base + 4 <= n) {
    *reinterpret_cast<int4*>(&row_start[base]) = make_int4(p0, p1, p2, p3);
  } else {
    if (base + 0 < n) row_start[base + 0] = p0;
    if (base + 1 < n) row_start[base + 1] = p1;
    if (base + 2 < n) row_start[base + 2] = p2;
    if (base + 3 < n) row_start[base + 3] = p3;
  }
}

// ---- LDS-tiled fp32 GEMM: G[r][c] = (X[r][:].W[:][c]) * (DINV?dinv[r]:1) + (BIAS?bias[c]:0)
template <int K, int C, bool DINV, bool BIAS>
__global__ __launch_bounds__(256) void gemm_scale_kernel(const float* __restrict__ X,
                                                         const float* __restrict__ W,
                                                         const float* __restrict__ dinv,
                                                         const float* __restrict__ bias,
                                                         float* __restrict__ G, int n) {
  constexpr int Cp = ((C + 63) / 64) * 64;  // 64 or 128
  constexpr int CQ = Cp / 4;                // col-quads: 16 or 32
  constexpr int RG = 256 / CQ;              // row-groups: 16 or 8
  constexpr int RPB = RG * 4;               // rows per block: 64 or 32
  constexpr int XPITCH = K + 4;             // bank-offset pad, keeps 16B align
  constexpr int TPR = 256 / RPB;            // staging threads per row: 4 or 8

  __shared__ float Xs[RPB * XPITCH];
  __shared__ float Ws[K * Cp];

  const int tid = threadIdx.x;
  const int rbase = blockIdx.x * RPB;

  if (C == Cp) {
    for (int i = tid; i < K * C / 4; i += 256)
      reinterpret_cast<float4*>(Ws)[i] = reinterpret_cast<const float4*>(W)[i];
  } else {
    for (int i = tid; i < K * CQ; i += 256) {
      int k = i / CQ, cq = i % CQ, c = cq * 4;
      float4 v = make_float4(0.f, 0.f, 0.f, 0.f);
      if (c < C) v = *reinterpret_cast<const float4*>(&W[k * C + c]);  // C%4==0
      reinterpret_cast<float4*>(&Ws[k * Cp])[cq] = v;
    }
  }
  {
    int r = tid / TPR, j = tid % TPR;
    int grow = rbase + r;
    if (grow >= n) grow = n - 1;
    const float4* xr = reinterpret_cast<const float4*>(&X[(size_t)grow * K]);
    float4* xd = reinterpret_cast<float4*>(&Xs[r * XPITCH]);
#pragma unroll
    for (int it = 0; it < K / 4 / TPR; ++it) xd[j + it * TPR] = xr[j + it * TPR];
  }
  __syncthreads();

  const int ct = tid % CQ, rt = tid / CQ;
  const int c0 = ct * 4, r0 = rt * 4;

  float acc[4][4];
#pragma unroll
  for (int a = 0; a < 4; ++a)
#pragma unroll
    for (int b = 0; b < 4; ++b) acc[a][b] = 0.f;

  for (int k = 0; k < K; k += 4) {
    float4 w0 = *reinterpret_cast<const float4*>(&Ws[(k + 0) * Cp + c0]);
    float4 w1 = *reinterpret_cast<const float4*>(&Ws[(k + 1) * Cp + c0]);
    float4 w2 = *reinterpret_cast<const float4*>(&Ws[(k + 2) * Cp + c0]);
    float4 w3 = *reinterpret_cast<const float4*>(&Ws[(k + 3) * Cp + c0]);
#pragma unroll
    for (int rr = 0; rr < 4; ++rr) {
      float4 xv = *reinterpret_cast<const float4*>(&Xs[(r0 + rr) * XPITCH + k]);
      acc[rr][0] = fmaf(xv.w, w3.x, fmaf(xv.z, w2.x, fmaf(xv.y, w1.x, fmaf(xv.x, w0.x, acc[rr][0]))));
      acc[rr][1] = fmaf(xv.w, w3.y, fmaf(xv.z, w2.y, fmaf(xv.y, w1.y, fmaf(xv.x, w0.y, acc[rr][1]))));
      acc[rr][2] = fmaf(xv.w, w3.z, fmaf(xv.z, w2.z, fmaf(xv.y, w1.z, fmaf(xv.x, w0.z, acc[rr][2]))));
      acc[rr][3] = fmaf(xv.w, w3.w, fmaf(xv.z, w2.w, fmaf(xv.y, w1.w, fmaf(xv.x, w0.w, acc[rr][3]))));
    }
  }

#pragma unroll
  for (int rr = 0; rr < 4; ++rr) {
    int row = rbase + r0 + rr;
    if (row < n && c0 < C) {
      float s = DINV ? dinv[row] : 1.0f;
      float4 v;
      v.x = acc[rr][0] * s;
      v.y = acc[rr][1] * s;
      v.z = acc[rr][2] * s;
      v.w = acc[rr][3] * s;
      if (BIAS) {
        float4 bv = *reinterpret_cast<const float4*>(&bias[c0]);
        v.x += bv.x; v.y += bv.y; v.z += bv.z; v.w += bv.w;
      }
      *reinterpret_cast<float4*>(&G[(size_t)row * C + c0]) = v;
    }
  }
}

// out[d][c] = post( dinv[d]*(g[d][c] + sum_{e in row d} g[ssrc[e]][c]) [+ bias[c]] )
// post = relu if RELU; result additionally *dinv[d] if TSCALE (emits t for layer-3 reorder).
template <int C, bool RELU, bool BIAS, bool TSCALE>
__global__ __launch_bounds__(256) void agg_kernel(const float* __restrict__ g,
                                                  const int* __restrict__ row_start,
                                                  const int* __restrict__ ssrc,
                                                  const float* __restrict__ dinv,
                                                  const float* __restrict__ bias,
                                                  float* __restrict__ out, int n) {
  constexpr int TPN = (C <= 64) ? 64 : 128;  // threads per node
  constexpr int NPB = 256 / TPN;             // nodes per block
  int local = threadIdx.x / TPN;
  int c = threadIdx.x % TPN;
  int node = blockIdx.x * NPB + local;
  if (node >= n || c >= C) return;
  int e0 = row_start[node];
  int e1 = row_start[node + 1];
  float acc = g[(size_t)node * C + c];       // self-loop term
  int e = e0;
  for (; e + 15 < e1; e += 16) {             // 16 outstanding gathers (latency hiding)
    int s[16];
#pragma unroll
    for (int i = 0; i < 16; ++i) s[i] = ssrc[e + i];
    float v[16];
#pragma unroll
    for (int i = 0; i < 16; ++i) v[i] = g[(size_t)s[i] * C + c];
#pragma unroll
    for (int i = 0; i < 16; ++i) acc += v[i];
  }
  for (; e + 3 < e1; e += 4) {
    int s0 = ssrc[e + 0], s1 = ssrc[e + 1], s2 = ssrc[e + 2], s3 = ssrc[e + 3];
    float v0 = g[(size_t)s0 * C + c];
    float v1 = g[(size_t)s1 * C + c];
    float v2 = g[(size_t)s2 * C + c];
    float v3 = g[(size_t)s3 * C + c];
    acc += v0; acc += v1; acc += v2; acc += v3;
  }
  for (; e < e1; ++e) acc += g[(size_t)ssrc[e] * C + c];
  float di = dinv[node];
  float r = acc * di;
  if (BIAS) r += bias[c];
  if (RELU) r = fmaxf(r, 0.f);
  if (TSCALE) r *= di;
  out[(size_t)node * C + c] = r;
}

extern "C" void kernel_launch(void* const* d_in, const int* in_sizes, int n_in,
                              void* d_out, int out_size, void* d_ws, size_t ws_size,
                              hipStream_t stream) {
  const float* x = (const float*)d_in[0];
  const int* ei = (const int*)d_in[1];
  const float* W1 = (const float*)d_in[2];
  const float* b1 = (const float*)d_in[3];
  const float* W2 = (const float*)d_in[4];
  const float* b2 = (const float*)d_in[5];
  const float* W3 = (const float*)d_in[6];
  const float* b3 = (const float*)d_in[7];
  float* out = (float*)d_out;

  const int n = in_sizes[0] / IN_DIM;  // 100000
  const int E = in_sizes[1] / 2;       // 1600000
  const int* src = ei;
  const int* dst = ei + E;
  const int nbuck = (n + LMASK) >> LSHIFT;        // 782
  const int nchunk = (E + CHUNK - 1) / CHUNK;     // 196

  char* p = (char*)d_ws;
  auto alloc = [&](size_t bytes) {
    char* q = p;
    p += (bytes + 255) & ~(size_t)255;
    return q;
  };
  float* dinv = (float*)alloc((size_t)n * 4);
  int* row_start = (int*)alloc((size_t)(n + 1) * 4);
  int* cnt = (int*)alloc((size_t)n * 4);
  int* blocksum = (int*)alloc((size_t)1024 * 4);
  int* btotal = (int*)alloc((size_t)MAXBUCK * 4);
  int* bbase = (int*)alloc((size_t)(MAXBUCK + 1) * 4);
  int* H = (int*)alloc((size_t)nchunk * nbuck * 4);
  int* packed = (int*)alloc((size_t)E * 4);
  int* ssrc = (int*)alloc((size_t)E * 4);
  float* bufG = (float*)alloc((size_t)n * HID * 4);
  float* bufH = (float*)alloc((size_t)n * HID * 4);

  const int NB = (n + SCAN_TILE - 1) / SCAN_TILE;  // 98 node-scan blocks
  const int BGRID = (nbuck + 255) / 256;           // 4

  // ---- CSR build via 2-pass radix sort (once; shared by all 3 layers) ----
  coarse_hist_kernel<<<nchunk, 256, 0, stream>>>(dst, H, E, nbuck);
  btotal_kernel<<<BGRID, 256, 0, stream>>>(H, btotal, nchunk, nbuck);
  bbase_scan_kernel<<<1, 1024, 0, stream>>>(btotal, bbase, nbuck);
  chunk_offset_kernel<<<BGRID, 256, 0, stream>>>(H, bbase, nchunk, nbuck);
  coarse_scatter_kernel<<<nchunk, 256, 0, stream>>>(src, dst, H, packed, E, nbuck);
  fine_count_kernel<<<nbuck, 256, 0, stream>>>(packed, bbase, cnt, n);
  dinv_kernel<<<(n + 255) / 256, 256, 0, stream>>>(cnt, dinv, n);
  scan_partial_kernel<<<NB, 256, 0, stream>>>(cnt, blocksum, n);
  scan_blocksums_kernel<<<1, 1024, 0, stream>>>(blocksum, &row_start[n], NB);
  scan_final_kernel<<<NB, 256, 0, stream>>>(cnt, blocksum, row_start, n);
  fine_scatter_kernel<<<nbuck, 256, 0, stream>>>(packed, bbase, row_start, ssrc, n);

  // ---- layer 1: g1=(x W1)*dinv_row ; h1=relu(agg*dinv + b1) ----
  gemm_scale_kernel<IN_DIM, HID, true, false><<<(n + 63) / 64, 256, 0, stream>>>(x, W1, dinv, nullptr, bufG, n);
  agg_kernel<HID, true, true, false><<<(n + 3) / 4, 256, 0, stream>>>(bufG, row_start, ssrc, dinv, b1, bufH, n);

  // ---- layer 2: g2=(h1 W2)*dinv_row ; t = relu(agg*dinv + b2) * dinv  (pre-scaled for L3) ----
  gemm_scale_kernel<HID, HID, true, false><<<(n + 63) / 64, 256, 0, stream>>>(bufH, W2, dinv, nullptr, bufG, n);
  agg_kernel<HID, true, true, true><<<(n + 3) / 4, 256, 0, stream>>>(bufG, row_start, ssrc, dinv, b2, bufH, n);

  // ---- layer 3 (reordered): z = dinv*(t + sum t[s]) ; out = z W3 + b3 ----
  agg_kernel<HID, false, false, false><<<(n + 3) / 4, 256, 0, stream>>>(bufH, row_start, ssrc, dinv, nullptr, bufG, n);
  gemm_scale_kernel<HID, OUT_DIM, false, true><<<(n + 31) / 32, 256, 0, stream>>>(bufG, W3, dinv, b3, out, n);
}

// Round 7
// 430.281 us; speedup vs baseline: 2.6201x; 1.3307x over previous
//
#include <hip/hip_runtime.h>
#include <math.h>

// GCN 3-layer: out = Â relu(Â relu(Â x W1 + b1) W2 + b2) W3 + b3, Â = D^-1/2(A+I)D^-1/2
// Layer 3 reordered: Â(h2 W3) = (Â h2) W3  -> aggregate in 64-dim, then GEMM 64->112.
// CSR built once per launch via 2-pass radix sort on dst.

#define IN_DIM 128
#define HID 64
#define OUT_DIM 112
#define SCAN_TILE 1024   // elems per node-scan block: 256 threads x 4
#define LSHIFT 7         // 128 nodes per fine bucket
#define LMASK 127
#define MAXBUCK 1024     // supports n <= 131072
#define CHUNK 8192       // edges per coarse-pass block

// ---- pass 1a: per-chunk histogram of coarse buckets -> H[chunk*nbuck + b] ----
__global__ __launch_bounds__(256) void coarse_hist_kernel(const int* __restrict__ dst,
                                                          int* __restrict__ H,
                                                          int E, int nbuck) {
  __shared__ int hist[MAXBUCK];
  for (int i = threadIdx.x; i < nbuck; i += 256) hist[i] = 0;
  __syncthreads();
  int lo = blockIdx.x * CHUNK;
  int hi = min(E, lo + CHUNK);
  for (int i = lo + threadIdx.x; i < hi; i += 256)
    atomicAdd(&hist[dst[i] >> LSHIFT], 1);
  __syncthreads();
  int* Hrow = &H[(size_t)blockIdx.x * nbuck];
  for (int i = threadIdx.x; i < nbuck; i += 256) Hrow[i] = hist[i];
}

// ---- pass 1b: column totals of H -> btotal[b].  One WAVE per bucket. ----
__global__ __launch_bounds__(256) void btotal_kernel(const int* __restrict__ H,
                                                     int* __restrict__ btotal,
                                                     int nchunk, int nbuck) {
  int wv = threadIdx.x >> 6, lane = threadIdx.x & 63;
  int b = blockIdx.x * 4 + wv;
  if (b >= nbuck) return;
  int s = 0;
  for (int c = lane; c < nchunk; c += 64) s += H[(size_t)c * nbuck + b];
#pragma unroll
  for (int off = 1; off < 64; off <<= 1) s += __shfl_xor(s, off);
  if (lane == 0) btotal[b] = s;
}

// ---- pass 1c: exclusive scan of btotal -> bbase[0..nbuck] (single block) ----
__global__ __launch_bounds__(1024) void bbase_scan_kernel(const int* __restrict__ btotal,
                                                          int* __restrict__ bbase, int nbuck) {
  __shared__ int sh[1024];
  int t = threadIdx.x;
  int v = (t < nbuck) ? btotal[t] : 0;
  sh[t] = v;
  __syncthreads();
  for (int off = 1; off < 1024; off <<= 1) {
    int u = (t >= off) ? sh[t - off] : 0;
    __syncthreads();
    sh[t] += u;
    __syncthreads();
  }
  if (t < nbuck) bbase[t] = sh[t] - v;
  if (t == 1023) bbase[nbuck] = sh[1023];
}

// ---- pass 1d: H[c][b] <- bbase[b] + prefix over chunks.  One WAVE per bucket,
// shfl-scan over 64 chunks at a time (parallel; replaces 196-deep serial loop). ----
__global__ __launch_bounds__(256) void chunk_offset_kernel(int* __restrict__ H,
                                                           const int* __restrict__ bbase,
                                                           int nchunk, int nbuck) {
  int wv = threadIdx.x >> 6, lane = threadIdx.x & 63;
  int b = blockIdx.x * 4 + wv;
  if (b >= nbuck) return;
  int run = bbase[b];
  for (int c0 = 0; c0 < nchunk; c0 += 64) {
    int c = c0 + lane;
    int v = (c < nchunk) ? H[(size_t)c * nbuck + b] : 0;
    int incl = v;
#pragma unroll
    for (int off = 1; off < 64; off <<= 1) {
      int u = __shfl_up(incl, off);
      if (lane >= off) incl += u;
    }
    if (c < nchunk) H[(size_t)c * nbuck + b] = run + incl - v;
    run += __shfl(incl, 63);
  }
}

// ---- pass 1e: scatter edges into coarse-bucket runs as packed (src<<7 | dst&127) ----
__global__ __launch_bounds__(256) void coarse_scatter_kernel(const int* __restrict__ src,
                                                             const int* __restrict__ dst,
                                                             const int* __restrict__ H,
                                                             int* __restrict__ packed,
                                                             int E, int nbuck) {
  __shared__ int cur[MAXBUCK];
  const int* Hrow = &H[(size_t)blockIdx.x * nbuck];
  for (int i = threadIdx.x; i < nbuck; i += 256) cur[i] = Hrow[i];
  __syncthreads();
  int lo = blockIdx.x * CHUNK;
  int hi = min(E, lo + CHUNK);
  for (int i = lo + threadIdx.x; i < hi; i += 256) {
    int s = src[i], d = dst[i];
    int b = d >> LSHIFT;
    int pos = atomicAdd(&cur[b], 1);
    packed[pos] = (s << LSHIFT) | (d & LMASK);
  }
}

// ---- pass 2a: per-bucket node-degree histogram -> cnt ----
__global__ __launch_bounds__(256) void fine_count_kernel(const int* __restrict__ packed,
                                                         const int* __restrict__ bbase,
                                                         int* __restrict__ cnt, int n) {
  int b = blockIdx.x;
  __shared__ int hist[128];
  int t = threadIdx.x;
  if (t < 128) hist[t] = 0;
  __syncthreads();
  int e0 = bbase[b], e1 = bbase[b + 1];
  for (int e = e0 + t; e < e1; e += 256) atomicAdd(&hist[packed[e] & LMASK], 1);
  __syncthreads();
  int node = b * 128 + t;
  if (t < 128 && node < n) cnt[node] = hist[t];
}

// ---- pass 2b: per-bucket fill of ssrc ----
__global__ __launch_bounds__(256) void fine_scatter_kernel(const int* __restrict__ packed,
                                                           const int* __restrict__ bbase,
                                                           const int* __restrict__ row_start,
                                                           int* __restrict__ ssrc, int n) {
  int b = blockIdx.x;
  __shared__ int cur[128];
  int t = threadIdx.x;
  if (t < 128) {
    int node = b * 128 + t;
    cur[t] = (node < n) ? row_start[node] : 0;
  }
  __syncthreads();
  int e0 = bbase[b], e1 = bbase[b + 1];
  for (int e = e0 + t; e < e1; e += 256) {
    int p = packed[e];
    int slot = atomicAdd(&cur[p & LMASK], 1);
    ssrc[slot] = p >> LSHIFT;
  }
}

__global__ __launch_bounds__(256) void dinv_kernel(const int* __restrict__ cnt,
                                                   float* __restrict__ dinv, int n) {
  int i = blockIdx.x * 256 + threadIdx.x;
  if (i < n) dinv[i] = 1.0f / sqrtf((float)(cnt[i] + 1));  // +1 = self loop
}

// ---- hierarchical exclusive scan over node counts -> row_start ----

__global__ __launch_bounds__(256) void scan_partial_kernel(const int* __restrict__ cnt,
                                                           int* __restrict__ blocksum,
                                                           int n) {
  int t = threadIdx.x;
  int base = blockIdx.x * SCAN_TILE + t * 4;
  int s = 0;
  if (base + 4 <= n) {
    int4 v = *reinterpret_cast<const int4*>(&cnt[base]);
    s = v.x + v.y + v.z + v.w;
  } else {
    for (int i = 0; i < 4; ++i)
      if (base + i < n) s += cnt[base + i];
  }
#pragma unroll
  for (int off = 1; off < 64; off <<= 1) s += __shfl_xor(s, off);
  __shared__ int wsum[4];
  int lane = t & 63, wv = t >> 6;
  if (lane == 0) wsum[wv] = s;
  __syncthreads();
  if (t == 0) blocksum[blockIdx.x] = wsum[0] + wsum[1] + wsum[2] + wsum[3];
}

__global__ __launch_bounds__(1024) void scan_blocksums_kernel(int* __restrict__ blocksum,
                                                              int* __restrict__ total_out,
                                                              int nb) {
  __shared__ int sh[1024];
  int t = threadIdx.x;
  int v = (t < nb) ? blocksum[t] : 0;
  sh[t] = v;
  __syncthreads();
  for (int off = 1; off < 1024; off <<= 1) {
    int u = (t >= off) ? sh[t - off] : 0;
    __syncthreads();
    sh[t] += u;
    __syncthreads();
  }
  if (t < nb) blocksum[t] = sh[t] - v;  // exclusive
  if (t == 1023) *total_out = sh[1023]; // grand total
}

__global__ __launch_bounds__(256) void scan_final_kernel(const int* __restrict__ cnt,
                                                         const int* __restrict__ blocksum,
                                                         int* __restrict__ row_start, int n) {
  int t = threadIdx.x;
  int base = blockIdx.x * SCAN_TILE + t * 4;
  int v0 = 0, v1 = 0, v2 = 0, v3 = 0;
  if (base + 4 <= n) {
    int4 v = *reinterpret_cast<const int4*>(&cnt[base]);
    v0 = v.x; v1 = v.y; v2 = v.z; v3 = v.w;
  } else {
    if (base + 0 < n) v0 = cnt[base + 0];
    if (base + 1 < n) v1 = cnt[base + 1];
    if (base + 2 < n) v2 = cnt[base + 2];
    if (base + 3 < n) v3 = cnt[base + 3];
  }
  int s = v0 + v1 + v2 + v3;
  __shared__ int sh[256];
  sh[t] = s;
  __syncthreads();
  for (int off = 1; off < 256; off <<= 1) {
    int u = (t >= off) ? sh[t - off] : 0;
    __syncthreads();
    sh[t] += u;
    __syncthreads();
  }
  int run = blocksum[blockIdx.x] + sh[t] - s;
  int p0 = run, p1 = run + v0, p2 = p1 + v1, p3 = p2 + v2;
  if (base + 4 <= n) {
    *reinterpret_cast<int4*>(&row_start[base]) = make_int4(p0, p1, p2, p3);
  } else {
    if (base + 0 < n) row_start[base + 0] = p0;
    if (base + 1 < n) row_start[base + 1] = p1;
    if (base + 2 < n) row_start[base + 2] = p2;
    if (base + 3 < n) row_start[base + 3] = p3;
  }
}

// ---- K-chunked LDS-tiled fp32 GEMM ----
// G[r][c] = (X[r][:].W[:][c]) * (DINV?dinv[r]:1) + (BIAS?bias[c]:0)
// BK-chunked staging keeps LDS <= 33KB; unroll 2 + launch_bounds(256,4) keep
// VGPR <= 128 -> 16 waves/CU (was: VGPR 240, 10% occupancy, 80us/dispatch).
template <int K, int C, int BK, bool DINV, bool BIAS>
__global__ __launch_bounds__(256, 4) void gemm_scale_kernel(const float* __restrict__ X,
                                                            const float* __restrict__ W,
                                                            const float* __restrict__ dinv,
                                                            const float* __restrict__ bias,
                                                            float* __restrict__ G, int n) {
  constexpr int Cp = ((C + 63) / 64) * 64;  // 64 or 128
  constexpr int CQ = Cp / 4;                // col-quads: 16 or 32
  constexpr int RG = 256 / CQ;              // row-groups: 16 or 8
  constexpr int RPB = RG * 4;               // rows per block: 64 or 32
  constexpr int XP = BK + 4;                // padded LDS pitch (16B-aligned)
  constexpr int XQ = BK / 4;                // x quads per row per chunk
  constexpr int NXQ = RPB * XQ;             // x quads per chunk
  constexpr int NWQ = BK * CQ;              // w quads per chunk

  __shared__ float Xs[RPB * XP];
  __shared__ float Ws[BK * Cp];

  const int tid = threadIdx.x;
  const int rbase = blockIdx.x * RPB;
  const int ct = tid % CQ, rt = tid / CQ;
  const int c0 = ct * 4, r0 = rt * 4;

  float acc[4][4];
#pragma unroll
  for (int a = 0; a < 4; ++a)
#pragma unroll
    for (int b = 0; b < 4; ++b) acc[a][b] = 0.f;

  for (int kb = 0; kb < K; kb += BK) {
    if (kb > 0) __syncthreads();  // protect LDS reuse across chunks
    // stage X chunk (coalesced float4; tail rows clamped, stores guarded later)
#pragma unroll
    for (int q = tid; q < NXQ; q += 256) {
      int r = q / XQ, j = q % XQ;
      int grow = rbase + r;
      if (grow >= n) grow = n - 1;
      *reinterpret_cast<float4*>(&Xs[r * XP + j * 4]) =
          *reinterpret_cast<const float4*>(&X[(size_t)grow * K + kb + j * 4]);
    }
    // stage W chunk (zero-fill padded cols)
#pragma unroll
    for (int q = tid; q < NWQ; q += 256) {
      int k = q / CQ, cq = q % CQ, c = cq * 4;
      float4 v = make_float4(0.f, 0.f, 0.f, 0.f);
      if (c < C) v = *reinterpret_cast<const float4*>(&W[(size_t)(kb + k) * C + c]);
      *reinterpret_cast<float4*>(&Ws[k * Cp + c]) = v;
    }
    __syncthreads();

#pragma unroll 2
    for (int k = 0; k < BK; k += 4) {
      float4 w0 = *reinterpret_cast<const float4*>(&Ws[(k + 0) * Cp + c0]);
      float4 w1 = *reinterpret_cast<const float4*>(&Ws[(k + 1) * Cp + c0]);
      float4 w2 = *reinterpret_cast<const float4*>(&Ws[(k + 2) * Cp + c0]);
      float4 w3 = *reinterpret_cast<const float4*>(&Ws[(k + 3) * Cp + c0]);
#pragma unroll
      for (int rr = 0; rr < 4; ++rr) {
        float4 xv = *reinterpret_cast<const float4*>(&Xs[(r0 + rr) * XP + k]);
        acc[rr][0] = fmaf(xv.w, w3.x, fmaf(xv.z, w2.x, fmaf(xv.y, w1.x, fmaf(xv.x, w0.x, acc[rr][0]))));
        acc[rr][1] = fmaf(xv.w, w3.y, fmaf(xv.z, w2.y, fmaf(xv.y, w1.y, fmaf(xv.x, w0.y, acc[rr][1]))));
        acc[rr][2] = fmaf(xv.w, w3.z, fmaf(xv.z, w2.z, fmaf(xv.y, w1.z, fmaf(xv.x, w0.z, acc[rr][2]))));
        acc[rr][3] = fmaf(xv.w, w3.w, fmaf(xv.z, w2.w, fmaf(xv.y, w1.w, fmaf(xv.x, w0.w, acc[rr][3]))));
      }
    }
  }

#pragma unroll
  for (int rr = 0; rr < 4; ++rr) {
    int row = rbase + r0 + rr;
    if (row < n && c0 < C) {
      float s = DINV ? dinv[row] : 1.0f;
      float4 v;
      v.x = acc[rr][0] * s;
      v.y = acc[rr][1] * s;
      v.z = acc[rr][2] * s;
      v.w = acc[rr][3] * s;
      if (BIAS) {
        float4 bv = *reinterpret_cast<const float4*>(&bias[c0]);
        v.x += bv.x; v.y += bv.y; v.z += bv.z; v.w += bv.w;
      }
      *reinterpret_cast<float4*>(&G[(size_t)row * C + c0]) = v;
    }
  }
}

// out[d][c] = post( dinv[d]*(g[d][c] + sum_{e in row d} g[ssrc[e]][c]) [+ bias[c]] )
template <int C, bool RELU, bool BIAS, bool TSCALE>
__global__ __launch_bounds__(256) void agg_kernel(const float* __restrict__ g,
                                                  const int* __restrict__ row_start,
                                                  const int* __restrict__ ssrc,
                                                  const float* __restrict__ dinv,
                                                  const float* __restrict__ bias,
                                                  float* __restrict__ out, int n) {
  constexpr int TPN = (C <= 64) ? 64 : 128;  // threads per node
  constexpr int NPB = 256 / TPN;             // nodes per block
  int local = threadIdx.x / TPN;
  int c = threadIdx.x % TPN;
  int node = blockIdx.x * NPB + local;
  if (node >= n || c >= C) return;
  int e0 = row_start[node];
  int e1 = row_start[node + 1];
  float acc = g[(size_t)node * C + c];       // self-loop term
  int e = e0;
  for (; e + 15 < e1; e += 16) {             // 16 outstanding gathers (latency hiding)
    int s[16];
#pragma unroll
    for (int i = 0; i < 16; ++i) s[i] = ssrc[e + i];
    float v[16];
#pragma unroll
    for (int i = 0; i < 16; ++i) v[i] = g[(size_t)s[i] * C + c];
#pragma unroll
    for (int i = 0; i < 16; ++i) acc += v[i];
  }
  for (; e + 3 < e1; e += 4) {
    int s0 = ssrc[e + 0], s1 = ssrc[e + 1], s2 = ssrc[e + 2], s3 = ssrc[e + 3];
    float v0 = g[(size_t)s0 * C + c];
    float v1 = g[(size_t)s1 * C + c];
    float v2 = g[(size_t)s2 * C + c];
    float v3 = g[(size_t)s3 * C + c];
    acc += v0; acc += v1; acc += v2; acc += v3;
  }
  for (; e < e1; ++e) acc += g[(size_t)ssrc[e] * C + c];
  float di = dinv[node];
  float r = acc * di;
  if (BIAS) r += bias[c];
  if (RELU) r = fmaxf(r, 0.f);
  if (TSCALE) r *= di;
  out[(size_t)node * C + c] = r;
}

extern "C" void kernel_launch(void* const* d_in, const int* in_sizes, int n_in,
                              void* d_out, int out_size, void* d_ws, size_t ws_size,
                              hipStream_t stream) {
  const float* x = (const float*)d_in[0];
  const int* ei = (const int*)d_in[1];
  const float* W1 = (const float*)d_in[2];
  const float* b1 = (const float*)d_in[3];
  const float* W2 = (const float*)d_in[4];
  const float* b2 = (const float*)d_in[5];
  const float* W3 = (const float*)d_in[6];
  const float* b3 = (const float*)d_in[7];
  float* out = (float*)d_out;

  const int n = in_sizes[0] / IN_DIM;  // 100000
  const int E = in_sizes[1] / 2;       // 1600000
  const int* src = ei;
  const int* dst = ei + E;
  const int nbuck = (n + LMASK) >> LSHIFT;        // 782
  const int nchunk = (E + CHUNK - 1) / CHUNK;     // 196

  char* p = (char*)d_ws;
  auto alloc = [&](size_t bytes) {
    char* q = p;
    p += (bytes + 255) & ~(size_t)255;
    return q;
  };
  float* dinv = (float*)alloc((size_t)n * 4);
  int* row_start = (int*)alloc((size_t)(n + 1) * 4);
  int* cnt = (int*)alloc((size_t)n * 4);
  int* blocksum = (int*)alloc((size_t)1024 * 4);
  int* btotal = (int*)alloc((size_t)MAXBUCK * 4);
  int* bbase = (int*)alloc((size_t)(MAXBUCK + 1) * 4);
  int* H = (int*)alloc((size_t)nchunk * nbuck * 4);
  int* packed = (int*)alloc((size_t)E * 4);
  int* ssrc = (int*)alloc((size_t)E * 4);
  float* bufG = (float*)alloc((size_t)n * HID * 4);
  float* bufH = (float*)alloc((size_t)n * HID * 4);

  const int NB = (n + SCAN_TILE - 1) / SCAN_TILE;  // 98 node-scan blocks
  const int WGRID = (nbuck + 3) / 4;               // wave-per-bucket grids

  // ---- CSR build via 2-pass radix sort (once; shared by all 3 layers) ----
  coarse_hist_kernel<<<nchunk, 256, 0, stream>>>(dst, H, E, nbuck);
  btotal_kernel<<<WGRID, 256, 0, stream>>>(H, btotal, nchunk, nbuck);
  bbase_scan_kernel<<<1, 1024, 0, stream>>>(btotal, bbase, nbuck);
  chunk_offset_kernel<<<WGRID, 256, 0, stream>>>(H, bbase, nchunk, nbuck);
  coarse_scatter_kernel<<<nchunk, 256, 0, stream>>>(src, dst, H, packed, E, nbuck);
  fine_count_kernel<<<nbuck, 256, 0, stream>>>(packed, bbase, cnt, n);
  dinv_kernel<<<(n + 255) / 256, 256, 0, stream>>>(cnt, dinv, n);
  scan_partial_kernel<<<NB, 256, 0, stream>>>(cnt, blocksum, n);
  scan_blocksums_kernel<<<1, 1024, 0, stream>>>(blocksum, &row_start[n], NB);
  scan_final_kernel<<<NB, 256, 0, stream>>>(cnt, blocksum, row_start, n);
  fine_scatter_kernel<<<nbuck, 256, 0, stream>>>(packed, bbase, row_start, ssrc, n);

  // ---- layer 1: g1=(x W1)*dinv_row ; h1=relu(agg*dinv + b1) ----
  gemm_scale_kernel<IN_DIM, HID, 64, true, false><<<(n + 63) / 64, 256, 0, stream>>>(x, W1, dinv, nullptr, bufG, n);
  agg_kernel<HID, true, true, false><<<(n + 3) / 4, 256, 0, stream>>>(bufG, row_start, ssrc, dinv, b1, bufH, n);

  // ---- layer 2: g2=(h1 W2)*dinv_row ; t = relu(agg*dinv + b2) * dinv  (pre-scaled for L3) ----
  gemm_scale_kernel<HID, HID, 64, true, false><<<(n + 63) / 64, 256, 0, stream>>>(bufH, W2, dinv, nullptr, bufG, n);
  agg_kernel<HID, true, true, true><<<(n + 3) / 4, 256, 0, stream>>>(bufG, row_start, ssrc, dinv, b2, bufH, n);

  // ---- layer 3 (reordered): z = dinv*(t + sum t[s]) ; out = z W3 + b3 ----
  agg_kernel<HID, false, false, false><<<(n + 3) / 4, 256, 0, stream>>>(bufH, row_start, ssrc, dinv, nullptr, bufG, n);
  gemm_scale_kernel<HID, OUT_DIM, 32, false, true><<<(n + 31) / 32, 256, 0, stream>>>(bufG, W3, dinv, b3, out, n);
}